// Round 4
// baseline (507.942 us; speedup 1.0000x reference)
//
#include <hip/hip_runtime.h>
#include <hip/hip_bf16.h>
#include <math.h>

// ---------------------------------------------------------------------------
// FederatedPPOAgent: 3x GCNConv (N=100k, E=3.2M, D=128) + actor/critic MLPs.
//
// R13 changes vs R12:
//  - headsAC_k: actor+critic merged into ONE kernel. h3 read once (was twice,
//    12.8MB each); B-fragments read direct from global (32KB tables, L2-hot
//    -- the global-B MFMA pattern proven in R10 phase 2). LDS 26.6KB (As+A1
//    only, A1 reused actor->critic), barrier-free.
//  - chunk_sum_k folded into sum_hist_dinv_k (block reduce -> bsum).
//  - scan_mid_k folded into scan_off_pad_k (per-block boff = sum bsum[j<b],
//    ~391 L2-hot ints; last block writes rowptr[N]). 3 launches removed.
//  - gemm2 grids: 512 -> 768 (<128,128>, 3 blocks/CU by LDS) / 1024 (<128,64>).
//  - agg128/agg64/gemm2/CSR core unchanged (gather at established HW ceiling:
//    66us, 2.9 TB/s, 162MB FETCH).
// ---------------------------------------------------------------------------

#define WS_ALIGN(x) (((x) + 255) & ~(size_t)255)

constexpr int RNG  = 64;        // node ranges
constexpr int NRG  = 1563;      // nodes per range (64*1563 >= 100000)
constexpr int NB   = 1024;      // bucket-phase blocks
constexpr int CHK  = 16;        // per-range fill chunks

constexpr float S_FP8     = 64.0f;
constexpr float S_FP8_INV = 1.0f / 64.0f;

using bf16x8 = __attribute__((ext_vector_type(8))) short;
using f32x4  = __attribute__((ext_vector_type(4))) float;
using f32x2  = __attribute__((ext_vector_type(2))) float;

__device__ __forceinline__ float b2f(unsigned short u) {
    return __uint_as_float(((unsigned int)u) << 16);
}
__device__ __forceinline__ unsigned short f2b(float f) {
    __hip_bfloat16 hb = __float2bfloat16(f);
    return *(unsigned short*)&hb;
}
__device__ __forceinline__ unsigned char f2fp8(float f) {
    return (unsigned char)(__builtin_amdgcn_cvt_pk_fp8_f32(f, f, 0, false) & 0xff);
}
__device__ __forceinline__ int pad8(int v) { return (v + 7) & ~7; }

// 8 fp8 (uint2) -> 4 packed-f32 accumulators
__device__ __forceinline__ void acc8(uint2 u, f32x2& a01, f32x2& a23,
                                     f32x2& a45, f32x2& a67) {
    a01 += __builtin_amdgcn_cvt_pk_f32_fp8((int)u.x, false);
    a23 += __builtin_amdgcn_cvt_pk_f32_fp8((int)u.x, true);
    a45 += __builtin_amdgcn_cvt_pk_f32_fp8((int)u.y, false);
    a67 += __builtin_amdgcn_cvt_pk_f32_fp8((int)u.y, true);
}

// ---------------- CSR build ----------------

__global__ __launch_bounds__(256) void bucket_count_k(
    const int* __restrict__ dst, int* __restrict__ bcnt, int E) {
    __shared__ int c64[RNG];
    int b = blockIdx.x, t = threadIdx.x;
    if (t < RNG) c64[t] = 0;
    __syncthreads();
    int ec = (E + NB - 1) / NB;
    int e0 = b * ec, e1 = min(E, e0 + ec);
    for (int e = e0 + t; e < e1; e += 256) {
        int d = __builtin_nontemporal_load(dst + e);
        atomicAdd(&c64[d / NRG], 1);
    }
    __syncthreads();
    if (t < RNG) bcnt[t * NB + b] = c64[t];
}

// block r: exclusive scan of bcnt[r][0..NB) -> base, total -> rtot[r]
__global__ __launch_bounds__(256) void rsum_k(
    const int* __restrict__ bcnt, int* __restrict__ base, int* __restrict__ rtot) {
    __shared__ int s[256];
    int r = blockIdx.x, t = threadIdx.x;
    const int* row = bcnt + (size_t)r * NB;
    int v[4], loc = 0;
#pragma unroll
    for (int j = 0; j < 4; j++) { v[j] = row[t * 4 + j]; loc += v[j]; }
    s[t] = loc;
    __syncthreads();
    for (int d = 1; d < 256; d <<= 1) {
        int x = (t >= d) ? s[t - d] : 0;
        __syncthreads();
        s[t] += x;
        __syncthreads();
    }
    int run = s[t] - loc;   // exclusive
    int* bp = base + (size_t)r * NB + t * 4;
#pragma unroll
    for (int j = 0; j < 4; j++) { bp[j] = run; run += v[j]; }
    if (t == 255) rtot[r] = s[255];
}

__global__ void rstart_k(const int* __restrict__ rtot, int* __restrict__ bstart, int E) {
    if (threadIdx.x == 0) {
        int run = 0;
        for (int r = 0; r < RNG; r++) { bstart[r] = run; run += rtot[r]; }
        bstart[RNG] = run;
    }
}

__global__ __launch_bounds__(256) void bucket_scatter_k(
    const int* __restrict__ src, const int* __restrict__ dst,
    const int* __restrict__ base, const int* __restrict__ bstart,
    unsigned* __restrict__ bucket, int E) {
    __shared__ int cur[RNG];
    int b = blockIdx.x, t = threadIdx.x;
    if (t < RNG) cur[t] = bstart[t] + base[(size_t)t * NB + b];
    __syncthreads();
    int ec = (E + NB - 1) / NB;
    int e0 = b * ec, e1 = min(E, e0 + ec);
    for (int e = e0 + t; e < e1; e += 256) {
        int d = __builtin_nontemporal_load(dst + e);
        int sv = __builtin_nontemporal_load(src + e);
        int r = d / NRG;
        int pos = atomicAdd(&cur[r], 1);
        bucket[pos] = ((unsigned)(d - r * NRG) << 17) | (unsigned)sv;
    }
}

__global__ __launch_bounds__(256) void hist_bucket_k(
    const unsigned* __restrict__ bucket, const int* __restrict__ bstart,
    int* __restrict__ hist) {
    __shared__ int h[NRG];
    int b = blockIdx.x, r = b & 63, c2 = b >> 6, t = threadIdx.x;
    for (int i = t; i < NRG; i += 256) h[i] = 0;
    int s0 = bstart[r], s1 = bstart[r + 1];
    int ec = (s1 - s0 + CHK - 1) / CHK;
    int e0 = s0 + c2 * ec, e1 = min(s1, e0 + ec);
    __syncthreads();
    for (int e = e0 + t; e < e1; e += 256) {
        unsigned v = __builtin_nontemporal_load(bucket + e);
        atomicAdd(&h[v >> 17], 1);
    }
    __syncthreads();
    int* out = hist + ((size_t)r * CHK + c2) * NRG;
    for (int i = t; i < NRG; i += 256) out[i] = h[i];
}

// per-node degree + dinv + per-block padded-count sum (chunk_sum folded in)
__global__ __launch_bounds__(256) void sum_hist_dinv_k(
    const int* __restrict__ hist, int* __restrict__ cnt,
    float* __restrict__ dinv, int* __restrict__ bsum, int N) {
    __shared__ int sd[256];
    int t = threadIdx.x;
    int i = blockIdx.x * 256 + t;
    int s = 0;
    if (i < N) {
        int r = i / NRG, li = i - r * NRG;
        const int* hp = hist + ((size_t)r * CHK) * NRG + li;
#pragma unroll
        for (int c = 0; c < CHK; c++) s += hp[(size_t)c * NRG];
        cnt[i] = s;
        dinv[i] = rsqrtf((float)s + 1.0f);   // +1: self loop
    }
    sd[t] = (i < N) ? pad8(s) : 0;
    __syncthreads();
    for (int d = 128; d > 0; d >>= 1) {
        if (t < d) sd[t] += sd[t + d];
        __syncthreads();
    }
    if (t == 0) bsum[blockIdx.x] = sd[0];
}

// scan_final + boff-from-bsum (scan_mid folded) + offsets + pad_col
__global__ void scan_off_pad_k(const int* __restrict__ cnt, const int* __restrict__ bsum,
                               int* __restrict__ rowptr, int* __restrict__ hist,
                               int* __restrict__ col, int N) {
    __shared__ int s[256];
    int t = threadIdx.x, b = blockIdx.x;

    // boff = sum of bsum[j] for j < b (bsum is L2-hot, <=391 ints)
    int part = 0;
    for (int j = t; j < b; j += 256) part += bsum[j];
    s[t] = part;
    __syncthreads();
    for (int d = 128; d > 0; d >>= 1) {
        if (t < d) s[t] += s[t + d];
        __syncthreads();
    }
    int boffv = s[0];
    __syncthreads();

    int i = b * 256 + t;
    int cv = (i < N) ? cnt[i] : 0;
    int v = pad8(cv);
    if (i >= N) v = 0;
    s[t] = v;
    __syncthreads();
    for (int d = 1; d < 256; d <<= 1) {
        int x = (t >= d) ? s[t - d] : 0;
        __syncthreads();
        s[t] += x;
        __syncthreads();
    }
    if (b == (int)gridDim.x - 1 && t == 255) rowptr[N] = boffv + s[255];
    if (i < N) {
        int rp = s[t] - v + boffv;
        rowptr[i] = rp;
        // offsets: hist[r][c][li] -> running cursor
        int r = i / NRG, li = i - r * NRG;
        int* hp = hist + ((size_t)r * CHK) * NRG + li;
        int run = rp;
#pragma unroll
        for (int c = 0; c < CHK; c++) {
            int hv = hp[(size_t)c * NRG];
            hp[(size_t)c * NRG] = run;
            run += hv;
        }
        // pad slots -> zero-row N
        for (int e = rp + cv; e < rp + v; e++) col[e] = N;
    }
}

__global__ __launch_bounds__(256) void fill2_k(
    const unsigned* __restrict__ bucket, const int* __restrict__ bstart,
    const int* __restrict__ hist, int* __restrict__ col) {
    __shared__ int cur[NRG];
    int b = blockIdx.x, r = b & 63, c2 = b >> 6, t = threadIdx.x;
    const int* hp = hist + ((size_t)r * CHK + c2) * NRG;
    for (int i = t; i < NRG; i += 256) cur[i] = hp[i];
    int s0 = bstart[r], s1 = bstart[r + 1];
    int ec = (s1 - s0 + CHK - 1) / CHK;
    int e0 = s0 + c2 * ec, e1 = min(s1, e0 + ec);
    __syncthreads();
    for (int e = e0 + t; e < e1; e += 256) {
        unsigned v = __builtin_nontemporal_load(bucket + e);
        int slot = atomicAdd(&cur[v >> 17], 1);   // LDS atomic
        col[slot] = (int)(v & 0x1FFFFu);
    }
}

// ---------------- weight prep: fp32 W[K][OUT] -> bf16 W^T[OUT][K] ----------------
// Layout: W1t(16384) W2t(16384) W3t(8192) Wh1t(16384: Wa1 rows 0..127,
// Wc1 rows 128..255, K=64) Wa2t(8192) Wc2t(8192)

__global__ __launch_bounds__(256) void prep_w_k(
    const float* __restrict__ W1, const float* __restrict__ W2,
    const float* __restrict__ W3, const float* __restrict__ Wa1,
    const float* __restrict__ Wc1, const float* __restrict__ Wa2,
    const float* __restrict__ Wc2, unsigned short* __restrict__ wt) {
    int i = blockIdx.x * 256 + threadIdx.x;   // 0..73727
    const float* W; int off, K, OUT;
    if (i < 16384)      { W = W1;  off = 0;     K = 128; OUT = 128; }
    else if (i < 32768) { W = W2;  off = 16384; K = 128; OUT = 128; }
    else if (i < 40960) { W = W3;  off = 32768; K = 128; OUT = 64; }
    else if (i < 49152) { W = Wa1; off = 40960; K = 64;  OUT = 128; }
    else if (i < 57344) { W = Wc1; off = 49152; K = 64;  OUT = 128; }
    else if (i < 65536) { W = Wa2; off = 57344; K = 128; OUT = 64; }
    else                { W = Wc2; off = 65536; K = 128; OUT = 64; }
    int j = i - off, k = j / OUT, n = j - k * OUT;
    wt[off + n * K + k] = f2b(W[j]);
}

// ---------------- gemm2: weights-stationary grid-stride MFMA GEMM ----------------
// EPI 0: fp8(acc * dinv[row] * S), unguarded rows (zero pad-row at N)

template <int K, int OUT, int EPI, bool AF32>
__global__ __launch_bounds__(256) void gemm2_k(
    const void* __restrict__ Xv, int ldx, const unsigned short* __restrict__ Wt,
    const float* __restrict__ sb, const float* __restrict__ w3b,
    const float* __restrict__ b3, void* __restrict__ Yv, int N, int NT) {
    constexpr int LDK = K + 8;
    __shared__ __align__(16) unsigned short Bs[OUT * LDK];
    __shared__ __align__(16) unsigned short As[64 * LDK];
    int t = threadIdx.x;

    // stage B once per block (visible after first in-loop barrier)
    for (int g = t; g < OUT * (K / 8); g += 256) {
        int r = g / (K / 8), q = g - r * (K / 8);
        *(uint4*)&Bs[r * LDK + q * 8] = *(const uint4*)(Wt + r * K + q * 8);
    }

    int wv = t >> 6, lane = t & 63;
    int lm = lane & 15, lq = lane >> 4;
    constexpr int CT = OUT / 16;

    for (int tile = blockIdx.x; tile < NT; tile += gridDim.x) {
        int rowBase = tile * 64;

        // stage A tile
        if constexpr (AF32) {
            const float* X = (const float*)Xv;
            for (int g = t; g < 64 * (K / 8); g += 256) {
                int r = g / (K / 8), q = g - r * (K / 8);
                int gr = rowBase + r;
                unsigned short us[8];
                if (gr < N) {
                    float4 v0 = *(const float4*)(X + (size_t)gr * ldx + q * 8);
                    float4 v1 = *(const float4*)(X + (size_t)gr * ldx + q * 8 + 4);
                    us[0] = f2b(v0.x); us[1] = f2b(v0.y); us[2] = f2b(v0.z); us[3] = f2b(v0.w);
                    us[4] = f2b(v1.x); us[5] = f2b(v1.y); us[6] = f2b(v1.z); us[7] = f2b(v1.w);
                } else {
#pragma unroll
                    for (int j = 0; j < 8; j++) us[j] = 0;
                }
                *(uint4*)&As[r * LDK + q * 8] = *(uint4*)us;
            }
        } else {
            const unsigned short* X = (const unsigned short*)Xv;
            for (int g = t; g < 64 * (K / 8); g += 256) {
                int r = g / (K / 8), q = g - r * (K / 8);
                int gr = rowBase + r;
                uint4 v = make_uint4(0, 0, 0, 0);
                if (gr < N) v = *(const uint4*)(X + (size_t)gr * ldx + q * 8);
                *(uint4*)&As[r * LDK + q * 8] = v;
            }
        }
        __syncthreads();

        f32x4 acc[CT];
#pragma unroll
        for (int c = 0; c < CT; c++) acc[c] = (f32x4){0.f, 0.f, 0.f, 0.f};

        const unsigned short* arow = &As[(wv * 16 + lm) * LDK + lq * 8];
#pragma unroll
        for (int kt = 0; kt < K / 32; kt++) {
            bf16x8 a = *(const bf16x8*)(arow + kt * 32);
#pragma unroll
            for (int c = 0; c < CT; c++) {
                bf16x8 b = *(const bf16x8*)&Bs[(c * 16 + lm) * LDK + kt * 32 + lq * 8];
                acc[c] = __builtin_amdgcn_mfma_f32_16x16x32_bf16(a, b, acc[c], 0, 0, 0);
            }
        }

        // epilogue: C/D layout col=lane&15, row=(lane>>4)*4+reg [m89/m91]
        int r0 = rowBase + wv * 16 + lq * 4;
        if constexpr (EPI == 0) {
#pragma unroll
            for (int r = 0; r < 4; r++) {
                int gr = r0 + r;
                float scale = (gr < N) ? sb[gr] * S_FP8 : 0.f;
#pragma unroll
                for (int c = 0; c < CT; c++) {
                    int colg = c * 16 + lm;
                    ((unsigned char*)Yv)[(size_t)gr * OUT + colg] = f2fp8(acc[c][r] * scale);
                }
            }
        }
        __syncthreads();   // protect As before next tile's staging
    }
}

// ---------------- aggregation (one node per wave; R9-proven) ----------------

template <bool RELU>
__global__ __launch_bounds__(256) void agg128_k(
    const unsigned char* __restrict__ H,   // [(Npad+64),128] fp8, rows>=N zero
    const int* __restrict__ rowptr, const int* __restrict__ col,
    const float* __restrict__ dinv, const float* __restrict__ bias,
    unsigned short* __restrict__ Y, int N, int Ecap) {
    int tid = threadIdx.x;
    int node = blockIdx.x * 4 + (tid >> 6);
    if (node >= N) return;
    int lane = tid & 63;
    int grp = lane >> 4;
    int li8 = (lane & 15) * 8;

    f32x2 a01 = {0.f, 0.f}, a23 = {0.f, 0.f}, a45 = {0.f, 0.f}, a67 = {0.f, 0.f};
    if (grp == 0) {
        uint2 u = *(const uint2*)(H + (size_t)node * 128 + li8);
        acc8(u, a01, a23, a45, a67);
    }

    int start = rowptr[node], end = rowptr[node + 1];
    for (int e0 = start; e0 < end; e0 += 64) {
        int cv = col[min(e0 + lane, Ecap - 1)];
        int quads = min(64, end - e0) >> 2;
        for (int q = 0; q < quads; q += 2) {
            int s0 = __shfl(cv, 4 * q + grp, 64);
            int s1 = __shfl(cv, 4 * q + 4 + grp, 64);
            uint2 u0 = *(const uint2*)(H + (size_t)s0 * 128 + li8);
            uint2 u1 = *(const uint2*)(H + (size_t)s1 * 128 + li8);
            acc8(u0, a01, a23, a45, a67);
            acc8(u1, a01, a23, a45, a67);
        }
    }

#pragma unroll
    for (int w = 16; w < 64; w <<= 1) {
        a01[0] += __shfl_xor(a01[0], w, 64); a01[1] += __shfl_xor(a01[1], w, 64);
        a23[0] += __shfl_xor(a23[0], w, 64); a23[1] += __shfl_xor(a23[1], w, 64);
        a45[0] += __shfl_xor(a45[0], w, 64); a45[1] += __shfl_xor(a45[1], w, 64);
        a67[0] += __shfl_xor(a67[0], w, 64); a67[1] += __shfl_xor(a67[1], w, 64);
    }

    if (grp == 0) {
        float dv = dinv[node] * S_FP8_INV;
        float4 b0 = *(const float4*)(bias + li8);
        float4 b1 = *(const float4*)(bias + li8 + 4);
        float o0 = a01[0] * dv + b0.x, o1 = a01[1] * dv + b0.y;
        float o2 = a23[0] * dv + b0.z, o3 = a23[1] * dv + b0.w;
        float o4 = a45[0] * dv + b1.x, o5 = a45[1] * dv + b1.y;
        float o6 = a67[0] * dv + b1.z, o7 = a67[1] * dv + b1.w;
        if (RELU) {
            o0 = fmaxf(o0, 0.f); o1 = fmaxf(o1, 0.f); o2 = fmaxf(o2, 0.f); o3 = fmaxf(o3, 0.f);
            o4 = fmaxf(o4, 0.f); o5 = fmaxf(o5, 0.f); o6 = fmaxf(o6, 0.f); o7 = fmaxf(o7, 0.f);
        }
        unsigned short us[8] = {f2b(o0), f2b(o1), f2b(o2), f2b(o3),
                                f2b(o4), f2b(o5), f2b(o6), f2b(o7)};
        *(uint4*)(Y + (size_t)node * 128 + li8) = *(uint4*)us;
    }
}

__global__ __launch_bounds__(256) void agg64_k(
    const unsigned char* __restrict__ H,   // [(Npad+64),64] fp8, rows>=N zero
    const int* __restrict__ rowptr, const int* __restrict__ col,
    const float* __restrict__ dinv, const float* __restrict__ bias,
    unsigned short* __restrict__ Y, int N, int Ecap) {
    int tid = threadIdx.x;
    int node = blockIdx.x * 4 + (tid >> 6);
    if (node >= N) return;
    int lane = tid & 63;
    int grp = lane >> 3;
    int li8 = (lane & 7) * 8;

    f32x2 a01 = {0.f, 0.f}, a23 = {0.f, 0.f}, a45 = {0.f, 0.f}, a67 = {0.f, 0.f};
    if (grp == 0) {
        uint2 u = *(const uint2*)(H + (size_t)node * 64 + li8);
        acc8(u, a01, a23, a45, a67);
    }

    int start = rowptr[node], end = rowptr[node + 1];
    for (int e0 = start; e0 < end; e0 += 64) {
        int cv = col[min(e0 + lane, Ecap - 1)];
        int octs = min(64, end - e0) >> 3;
        int o = 0;
        for (; o + 2 <= octs; o += 2) {
            int s0 = __shfl(cv, 8 * o + grp, 64);
            int s1 = __shfl(cv, 8 * o + 8 + grp, 64);
            uint2 u0 = *(const uint2*)(H + (size_t)s0 * 64 + li8);
            uint2 u1 = *(const uint2*)(H + (size_t)s1 * 64 + li8);
            acc8(u0, a01, a23, a45, a67);
            acc8(u1, a01, a23, a45, a67);
        }
        if (o < octs) {
            int s0 = __shfl(cv, 8 * o + grp, 64);
            uint2 u0 = *(const uint2*)(H + (size_t)s0 * 64 + li8);
            acc8(u0, a01, a23, a45, a67);
        }
    }

#pragma unroll
    for (int w = 8; w < 64; w <<= 1) {
        a01[0] += __shfl_xor(a01[0], w, 64); a01[1] += __shfl_xor(a01[1], w, 64);
        a23[0] += __shfl_xor(a23[0], w, 64); a23[1] += __shfl_xor(a23[1], w, 64);
        a45[0] += __shfl_xor(a45[0], w, 64); a45[1] += __shfl_xor(a45[1], w, 64);
        a67[0] += __shfl_xor(a67[0], w, 64); a67[1] += __shfl_xor(a67[1], w, 64);
    }

    if (grp == 0) {
        float dv = dinv[node] * S_FP8_INV;
        float4 b0 = *(const float4*)(bias + li8);
        float4 b1 = *(const float4*)(bias + li8 + 4);
        unsigned short us[8] = {
            f2b(a01[0] * dv + b0.x), f2b(a01[1] * dv + b0.y),
            f2b(a23[0] * dv + b0.z), f2b(a23[1] * dv + b0.w),
            f2b(a45[0] * dv + b1.x), f2b(a45[1] * dv + b1.y),
            f2b(a67[0] * dv + b1.z), f2b(a67[1] * dv + b1.w)};
        *(uint4*)(Y + (size_t)node * 64 + li8) = *(uint4*)us;
    }
}

// ---------------- fused actor+critic heads (merged, R13) ----------------
// Per 64-row tile, each wave handles its 16 rows end-to-end, barrier-free:
// stage h3 rows -> actor {L1 MFMA (B from global Wh1t rows 0..127) -> relu
// -> A1 -> L2 MFMA (Wa2t) -> logits/softmax -> out[0..8)} -> critic {L1
// (Wh1t rows 128..255) -> A1 (reused) -> L2 (Wc2t) -> value -> out[8]}.
// B-fragments read direct from global (32KB tables, L1/L2-hot). LDS 26.6KB.

__global__ __launch_bounds__(256) void headsAC_k(
    const unsigned short* __restrict__ h3,    // [N,64] bf16
    const unsigned short* __restrict__ Wh1t,  // [256][64] bf16 concat L1
    const float* __restrict__ ba1, const float* __restrict__ bc1,
    const unsigned short* __restrict__ Wa2t,  // [64][128] bf16
    const float* __restrict__ ba2,
    const unsigned short* __restrict__ Wc2t,  // [64][128] bf16
    const float* __restrict__ bc2,
    const float* __restrict__ Wa3, const float* __restrict__ ba3,
    const float* __restrict__ Wc3, const float* __restrict__ bc3,
    float* __restrict__ out, int N, int NT) {
    constexpr int LD64 = 72, LD128 = 136;
    __shared__ __align__(16) unsigned short As[4 * 16 * LD64];  //  9.2KB
    __shared__ __align__(16) unsigned short A1[4 * 16 * LD128]; // 17.4KB
    int t = threadIdx.x, wv = t >> 6, lane = t & 63;
    int lm = lane & 15, lq = lane >> 4;
    unsigned short* Asw = &As[wv * 16 * LD64];
    unsigned short* A1w = &A1[wv * 16 * LD128];

    for (int tile = blockIdx.x; tile < NT; tile += gridDim.x) {
        int rowBase = tile * 64 + wv * 16;

        // stage wave's 16 h3 rows (wave-private)
        for (int g = lane; g < 16 * 8; g += 64) {
            int r = g >> 3, q = g & 7;
            int gr = rowBase + r;
            uint4 v = make_uint4(0, 0, 0, 0);
            if (gr < N) v = *(const uint4*)(h3 + (size_t)gr * 64 + q * 8);
            *(uint4*)&Asw[r * LD64 + q * 8] = v;
        }
        const unsigned short* arow = &Asw[lm * LD64 + lq * 8];
        int r0 = rowBase + lq * 4;

        // ================= actor =================
        {
            f32x4 acc1[8];
#pragma unroll
            for (int c = 0; c < 8; c++) acc1[c] = (f32x4){0.f, 0.f, 0.f, 0.f};
#pragma unroll
            for (int kt = 0; kt < 2; kt++) {
                bf16x8 a = *(const bf16x8*)(arow + kt * 32);
#pragma unroll
                for (int c = 0; c < 8; c++) {
                    bf16x8 b = *(const bf16x8*)(Wh1t + (size_t)(c * 16 + lm) * 64 + kt * 32 + lq * 8);
                    acc1[c] = __builtin_amdgcn_mfma_f32_16x16x32_bf16(a, b, acc1[c], 0, 0, 0);
                }
            }
#pragma unroll
            for (int r = 0; r < 4; r++) {
                int lr = lq * 4 + r;
#pragma unroll
                for (int c = 0; c < 8; c++) {
                    int colg = c * 16 + lm;
                    float v = fmaxf(acc1[c][r] + ba1[colg], 0.f);
                    A1w[lr * LD128 + colg] = f2b(v);
                }
            }

            f32x4 acc[4];
#pragma unroll
            for (int c = 0; c < 4; c++) acc[c] = (f32x4){0.f, 0.f, 0.f, 0.f};
            const unsigned short* arow2 = &A1w[lm * LD128 + lq * 8];
#pragma unroll
            for (int kt = 0; kt < 4; kt++) {
                bf16x8 a = *(const bf16x8*)(arow2 + kt * 32);
#pragma unroll
                for (int c = 0; c < 4; c++) {
                    bf16x8 b = *(const bf16x8*)(Wa2t + (size_t)(c * 16 + lm) * 128 + kt * 32 + lq * 8);
                    acc[c] = __builtin_amdgcn_mfma_f32_16x16x32_bf16(a, b, acc[c], 0, 0, 0);
                }
            }

            float l[4][8];
#pragma unroll
            for (int r = 0; r < 4; r++)
#pragma unroll
                for (int a = 0; a < 8; a++) l[r][a] = 0.f;
#pragma unroll
            for (int c = 0; c < 4; c++) {
                int colg = c * 16 + lm;
#pragma unroll
                for (int r = 0; r < 4; r++) {
                    float v = fmaxf(acc[c][r] + ba2[colg], 0.f);
#pragma unroll
                    for (int a = 0; a < 8; a++)
                        l[r][a] = fmaf(v, Wa3[colg * 8 + a], l[r][a]);
                }
            }
#pragma unroll
            for (int w = 1; w < 16; w <<= 1)
#pragma unroll
                for (int r = 0; r < 4; r++)
#pragma unroll
                    for (int a = 0; a < 8; a++)
                        l[r][a] += __shfl_xor(l[r][a], w, 64);
            if (lm < 8) {
#pragma unroll
                for (int r = 0; r < 4; r++) {
                    int gr = r0 + r;
                    if (gr < N) {
                        float lg[8], m = -1e30f;
#pragma unroll
                        for (int a = 0; a < 8; a++) { lg[a] = l[r][a] + ba3[a]; m = fmaxf(m, lg[a]); }
                        float sum = 0.f;
#pragma unroll
                        for (int a = 0; a < 8; a++) { lg[a] = expf(lg[a] - m); sum += lg[a]; }
                        out[(size_t)gr * 9 + lm] = lg[lm] / sum;
                    }
                }
            }
        }

        // ================= critic =================
        {
            f32x4 acc1[8];
#pragma unroll
            for (int c = 0; c < 8; c++) acc1[c] = (f32x4){0.f, 0.f, 0.f, 0.f};
#pragma unroll
            for (int kt = 0; kt < 2; kt++) {
                bf16x8 a = *(const bf16x8*)(arow + kt * 32);
#pragma unroll
                for (int c = 0; c < 8; c++) {
                    bf16x8 b = *(const bf16x8*)(Wh1t + (size_t)(128 + c * 16 + lm) * 64 + kt * 32 + lq * 8);
                    acc1[c] = __builtin_amdgcn_mfma_f32_16x16x32_bf16(a, b, acc1[c], 0, 0, 0);
                }
            }
#pragma unroll
            for (int r = 0; r < 4; r++) {
                int lr = lq * 4 + r;
#pragma unroll
                for (int c = 0; c < 8; c++) {
                    int colg = c * 16 + lm;
                    float v = fmaxf(acc1[c][r] + bc1[colg], 0.f);
                    A1w[lr * LD128 + colg] = f2b(v);
                }
            }

            f32x4 acc[4];
#pragma unroll
            for (int c = 0; c < 4; c++) acc[c] = (f32x4){0.f, 0.f, 0.f, 0.f};
            const unsigned short* arow2 = &A1w[lm * LD128 + lq * 8];
#pragma unroll
            for (int kt = 0; kt < 4; kt++) {
                bf16x8 a = *(const bf16x8*)(arow2 + kt * 32);
#pragma unroll
                for (int c = 0; c < 4; c++) {
                    bf16x8 b = *(const bf16x8*)(Wc2t + (size_t)(c * 16 + lm) * 128 + kt * 32 + lq * 8);
                    acc[c] = __builtin_amdgcn_mfma_f32_16x16x32_bf16(a, b, acc[c], 0, 0, 0);
                }
            }

            float lv[4] = {0.f, 0.f, 0.f, 0.f};
#pragma unroll
            for (int c = 0; c < 4; c++) {
                int colg = c * 16 + lm;
#pragma unroll
                for (int r = 0; r < 4; r++) {
                    float v = fmaxf(acc[c][r] + bc2[colg], 0.f);
                    lv[r] = fmaf(v, Wc3[colg], lv[r]);
                }
            }
#pragma unroll
            for (int w = 1; w < 16; w <<= 1)
#pragma unroll
                for (int r = 0; r < 4; r++) lv[r] += __shfl_xor(lv[r], w, 64);
            if (lm == 0) {
#pragma unroll
                for (int r = 0; r < 4; r++) {
                    int gr = r0 + r;
                    if (gr < N) out[(size_t)gr * 9 + 8] = lv[r] + bc3[0];
                }
            }
        }
    }
}

// ---------------- launch ----------------

extern "C" void kernel_launch(void* const* d_in, const int* in_sizes, int n_in,
                              void* d_out, int out_size, void* d_ws, size_t ws_size,
                              hipStream_t stream) {
    const float* x   = (const float*)d_in[0];
    const int*   ei  = (const int*)d_in[1];
    const float* W1  = (const float*)d_in[2];  const float* b1  = (const float*)d_in[3];
    const float* W2  = (const float*)d_in[4];  const float* b2  = (const float*)d_in[5];
    const float* W3  = (const float*)d_in[6];  const float* b3  = (const float*)d_in[7];
    const float* Wa1 = (const float*)d_in[8];  const float* ba1 = (const float*)d_in[9];
    const float* Wa2 = (const float*)d_in[10]; const float* ba2 = (const float*)d_in[11];
    const float* Wa3 = (const float*)d_in[12]; const float* ba3 = (const float*)d_in[13];
    const float* Wc1 = (const float*)d_in[14]; const float* bc1 = (const float*)d_in[15];
    const float* Wc2 = (const float*)d_in[16]; const float* bc2 = (const float*)d_in[17];
    const float* Wc3 = (const float*)d_in[18]; const float* bc3 = (const float*)d_in[19];
    float* out = (float*)d_out;

    const int N = in_sizes[0] / 128;     // 100000
    const int E = in_sizes[1] / 2;       // 3200000
    const int* src = ei;
    const int* dst = ei + E;
    const int Ecap = E + 8 * N;          // padded-CSR capacity
    const int Npad = ((N + 63) / 64) * 64;
    const int NT   = (N + 63) / 64;      // 1563 row tiles

    // workspace layout
    size_t off = 0;
    auto take = [&](size_t bytes) { size_t o = off; off = WS_ALIGN(off + bytes); return o; };
    char* ws = (char*)d_ws;
    unsigned short* h3     = (unsigned short*)(ws + take((size_t)N * 64 * 2));       // 12.8MB
    unsigned short* h      = (unsigned short*)(ws + take((size_t)N * 128 * 2));      // 25.6MB
    unsigned char*  hpr8   = (unsigned char*) (ws + take((size_t)(Npad + 64) * 128));// 12.8MB
    int*            col    = (int*)(ws + take((size_t)Ecap * 4));                    // 16MB
    unsigned short* wt     = (unsigned short*)(ws + take(73728 * 2));
    float* dinv   = (float*)(ws + take((size_t)(N + 64) * 4));
    int*   cnt    = (int*)  (ws + take((size_t)N * 4));
    int*   rowptr = (int*)  (ws + take((size_t)(N + 1) * 4));
    int*   bcnt   = (int*)  (ws + take((size_t)RNG * NB * 4));
    int*   base   = (int*)  (ws + take((size_t)RNG * NB * 4));
    int*   rtot   = (int*)  (ws + take(RNG * 4));
    int*   bstart = (int*)  (ws + take((RNG + 1) * 4));
    int*   bsum   = (int*)  (ws + take(512 * 4));
    // aliases: bucket (12.8MB) on h [h written first by agg128, after fill2];
    // hist (6.4MB) on h3 [h3 written only by agg64, after fill2].
    unsigned* bucket = (unsigned*)h;
    int* hist = (int*)h3;
    (void)ws_size; (void)n_in; (void)out_size;

    const int nb  = (N + 255) / 256;     // 391
    const int GG128 = 768;               // gemm2<128,128>: 3 blocks/CU by LDS
    const int GG64  = 1024;              // gemm2<128,64>: 4 blocks/CU by LDS

    prep_w_k<<<288, 256, 0, stream>>>(W1, W2, W3, Wa1, Wc1, Wa2, Wc2, wt);
    const unsigned short* W1t  = wt;
    const unsigned short* W2t  = wt + 16384;
    const unsigned short* W3t  = wt + 32768;
    const unsigned short* Wh1t = wt + 40960;   // [256][64] concat actor|critic L1
    const unsigned short* Wa2t = wt + 57344;
    const unsigned short* Wc2t = wt + 65536;

    // CSR build
    bucket_count_k<<<NB, 256, 0, stream>>>(dst, bcnt, E);
    rsum_k<<<RNG, 256, 0, stream>>>(bcnt, base, rtot);
    rstart_k<<<1, 64, 0, stream>>>(rtot, bstart, E);
    bucket_scatter_k<<<NB, 256, 0, stream>>>(src, dst, base, bstart, bucket, E);
    hist_bucket_k<<<RNG * CHK, 256, 0, stream>>>(bucket, bstart, hist);
    sum_hist_dinv_k<<<nb, 256, 0, stream>>>(hist, cnt, dinv, bsum, N);
    scan_off_pad_k<<<nb, 256, 0, stream>>>(cnt, bsum, rowptr, hist, col, N);
    fill2_k<<<RNG * CHK, 256, 0, stream>>>(bucket, bstart, hist, col);

    // GCN layer 1..3 (gemm -> fp8 -> gather-agg)
    gemm2_k<128, 128, 0, true><<<GG128, 256, 0, stream>>>(
        x, 128, W1t, dinv, nullptr, nullptr, hpr8, N, NT);
    agg128_k<true><<<(N + 3) / 4, 256, 0, stream>>>(hpr8, rowptr, col, dinv, b1, h, N, Ecap);
    gemm2_k<128, 128, 0, false><<<GG128, 256, 0, stream>>>(
        h, 128, W2t, dinv, nullptr, nullptr, hpr8, N, NT);
    agg128_k<true><<<(N + 3) / 4, 256, 0, stream>>>(hpr8, rowptr, col, dinv, b2, h, N, Ecap);
    gemm2_k<128, 64, 0, false><<<GG64, 256, 0, stream>>>(
        h, 128, W3t, dinv, nullptr, nullptr, hpr8, N, NT);
    agg64_k<<<(N + 3) / 4, 256, 0, stream>>>(hpr8, rowptr, col, dinv, b3, h3, N, Ecap);

    // merged actor+critic heads (h3 -> out)
    headsAC_k<<<1024, 256, 0, stream>>>(
        h3, Wh1t, ba1, bc1, Wa2t, ba2, Wc2t, bc2, Wa3, ba3, Wc3, bc3, out, N, NT);
}

// Round 5
// 465.321 us; speedup vs baseline: 1.0916x; 1.0916x over previous
//
#include <hip/hip_runtime.h>
#include <hip/hip_bf16.h>
#include <math.h>

// ---------------------------------------------------------------------------
// FederatedPPOAgent: 3x GCNConv (N=100k, E=3.2M, D=128) + actor/critic MLPs.
//
// R14 changes vs R13:
//  - headsAC_k REVERTED to R12's heads_k<2>/heads_k<3> pair. R13 post-mortem:
//    merged kernel hit VGPR=216 -> 2 waves/SIMD, occupancy 10%, and global-B
//    MFMA put ~200cy L2 latency in every dependent chain with nothing to hide
//    it -> 85us (slowest dispatch!). LDS-staged B + split kernels = ~14-18us
//    each, VGPR ~120, occupancy >40%. h3 double-read is L2/L3-absorbed
//    (FETCH was 6.6MB) so the merge bought nothing.
//  - KEPT from R13 (worth ~-32us): chunk_sum folded into sum_hist_dinv_k,
//    scan_mid folded into scan_off_pad_k, gemm2 grids 768/1024.
// ---------------------------------------------------------------------------

#define WS_ALIGN(x) (((x) + 255) & ~(size_t)255)

constexpr int RNG  = 64;        // node ranges
constexpr int NRG  = 1563;      // nodes per range (64*1563 >= 100000)
constexpr int NB   = 1024;      // bucket-phase blocks
constexpr int CHK  = 16;        // per-range fill chunks

constexpr float S_FP8     = 64.0f;
constexpr float S_FP8_INV = 1.0f / 64.0f;

using bf16x8 = __attribute__((ext_vector_type(8))) short;
using f32x4  = __attribute__((ext_vector_type(4))) float;
using f32x2  = __attribute__((ext_vector_type(2))) float;

__device__ __forceinline__ float b2f(unsigned short u) {
    return __uint_as_float(((unsigned int)u) << 16);
}
__device__ __forceinline__ unsigned short f2b(float f) {
    __hip_bfloat16 hb = __float2bfloat16(f);
    return *(unsigned short*)&hb;
}
__device__ __forceinline__ unsigned char f2fp8(float f) {
    return (unsigned char)(__builtin_amdgcn_cvt_pk_fp8_f32(f, f, 0, false) & 0xff);
}
__device__ __forceinline__ int pad8(int v) { return (v + 7) & ~7; }

// 8 fp8 (uint2) -> 4 packed-f32 accumulators
__device__ __forceinline__ void acc8(uint2 u, f32x2& a01, f32x2& a23,
                                     f32x2& a45, f32x2& a67) {
    a01 += __builtin_amdgcn_cvt_pk_f32_fp8((int)u.x, false);
    a23 += __builtin_amdgcn_cvt_pk_f32_fp8((int)u.x, true);
    a45 += __builtin_amdgcn_cvt_pk_f32_fp8((int)u.y, false);
    a67 += __builtin_amdgcn_cvt_pk_f32_fp8((int)u.y, true);
}

// ---------------- CSR build ----------------

__global__ __launch_bounds__(256) void bucket_count_k(
    const int* __restrict__ dst, int* __restrict__ bcnt, int E) {
    __shared__ int c64[RNG];
    int b = blockIdx.x, t = threadIdx.x;
    if (t < RNG) c64[t] = 0;
    __syncthreads();
    int ec = (E + NB - 1) / NB;
    int e0 = b * ec, e1 = min(E, e0 + ec);
    for (int e = e0 + t; e < e1; e += 256) {
        int d = __builtin_nontemporal_load(dst + e);
        atomicAdd(&c64[d / NRG], 1);
    }
    __syncthreads();
    if (t < RNG) bcnt[t * NB + b] = c64[t];
}

// block r: exclusive scan of bcnt[r][0..NB) -> base, total -> rtot[r]
__global__ __launch_bounds__(256) void rsum_k(
    const int* __restrict__ bcnt, int* __restrict__ base, int* __restrict__ rtot) {
    __shared__ int s[256];
    int r = blockIdx.x, t = threadIdx.x;
    const int* row = bcnt + (size_t)r * NB;
    int v[4], loc = 0;
#pragma unroll
    for (int j = 0; j < 4; j++) { v[j] = row[t * 4 + j]; loc += v[j]; }
    s[t] = loc;
    __syncthreads();
    for (int d = 1; d < 256; d <<= 1) {
        int x = (t >= d) ? s[t - d] : 0;
        __syncthreads();
        s[t] += x;
        __syncthreads();
    }
    int run = s[t] - loc;   // exclusive
    int* bp = base + (size_t)r * NB + t * 4;
#pragma unroll
    for (int j = 0; j < 4; j++) { bp[j] = run; run += v[j]; }
    if (t == 255) rtot[r] = s[255];
}

__global__ void rstart_k(const int* __restrict__ rtot, int* __restrict__ bstart, int E) {
    if (threadIdx.x == 0) {
        int run = 0;
        for (int r = 0; r < RNG; r++) { bstart[r] = run; run += rtot[r]; }
        bstart[RNG] = run;
    }
}

__global__ __launch_bounds__(256) void bucket_scatter_k(
    const int* __restrict__ src, const int* __restrict__ dst,
    const int* __restrict__ base, const int* __restrict__ bstart,
    unsigned* __restrict__ bucket, int E) {
    __shared__ int cur[RNG];
    int b = blockIdx.x, t = threadIdx.x;
    if (t < RNG) cur[t] = bstart[t] + base[(size_t)t * NB + b];
    __syncthreads();
    int ec = (E + NB - 1) / NB;
    int e0 = b * ec, e1 = min(E, e0 + ec);
    for (int e = e0 + t; e < e1; e += 256) {
        int d = __builtin_nontemporal_load(dst + e);
        int sv = __builtin_nontemporal_load(src + e);
        int r = d / NRG;
        int pos = atomicAdd(&cur[r], 1);
        bucket[pos] = ((unsigned)(d - r * NRG) << 17) | (unsigned)sv;
    }
}

__global__ __launch_bounds__(256) void hist_bucket_k(
    const unsigned* __restrict__ bucket, const int* __restrict__ bstart,
    int* __restrict__ hist) {
    __shared__ int h[NRG];
    int b = blockIdx.x, r = b & 63, c2 = b >> 6, t = threadIdx.x;
    for (int i = t; i < NRG; i += 256) h[i] = 0;
    int s0 = bstart[r], s1 = bstart[r + 1];
    int ec = (s1 - s0 + CHK - 1) / CHK;
    int e0 = s0 + c2 * ec, e1 = min(s1, e0 + ec);
    __syncthreads();
    for (int e = e0 + t; e < e1; e += 256) {
        unsigned v = __builtin_nontemporal_load(bucket + e);
        atomicAdd(&h[v >> 17], 1);
    }
    __syncthreads();
    int* out = hist + ((size_t)r * CHK + c2) * NRG;
    for (int i = t; i < NRG; i += 256) out[i] = h[i];
}

// per-node degree + dinv + per-block padded-count sum (chunk_sum folded in)
__global__ __launch_bounds__(256) void sum_hist_dinv_k(
    const int* __restrict__ hist, int* __restrict__ cnt,
    float* __restrict__ dinv, int* __restrict__ bsum, int N) {
    __shared__ int sd[256];
    int t = threadIdx.x;
    int i = blockIdx.x * 256 + t;
    int s = 0;
    if (i < N) {
        int r = i / NRG, li = i - r * NRG;
        const int* hp = hist + ((size_t)r * CHK) * NRG + li;
#pragma unroll
        for (int c = 0; c < CHK; c++) s += hp[(size_t)c * NRG];
        cnt[i] = s;
        dinv[i] = rsqrtf((float)s + 1.0f);   // +1: self loop
    }
    sd[t] = (i < N) ? pad8(s) : 0;
    __syncthreads();
    for (int d = 128; d > 0; d >>= 1) {
        if (t < d) sd[t] += sd[t + d];
        __syncthreads();
    }
    if (t == 0) bsum[blockIdx.x] = sd[0];
}

// scan_final + boff-from-bsum (scan_mid folded) + offsets + pad_col
__global__ void scan_off_pad_k(const int* __restrict__ cnt, const int* __restrict__ bsum,
                               int* __restrict__ rowptr, int* __restrict__ hist,
                               int* __restrict__ col, int N) {
    __shared__ int s[256];
    int t = threadIdx.x, b = blockIdx.x;

    // boff = sum of bsum[j] for j < b (bsum is L2-hot, <=391 ints)
    int part = 0;
    for (int j = t; j < b; j += 256) part += bsum[j];
    s[t] = part;
    __syncthreads();
    for (int d = 128; d > 0; d >>= 1) {
        if (t < d) s[t] += s[t + d];
        __syncthreads();
    }
    int boffv = s[0];
    __syncthreads();

    int i = b * 256 + t;
    int cv = (i < N) ? cnt[i] : 0;
    int v = pad8(cv);
    if (i >= N) v = 0;
    s[t] = v;
    __syncthreads();
    for (int d = 1; d < 256; d <<= 1) {
        int x = (t >= d) ? s[t - d] : 0;
        __syncthreads();
        s[t] += x;
        __syncthreads();
    }
    if (b == (int)gridDim.x - 1 && t == 255) rowptr[N] = boffv + s[255];
    if (i < N) {
        int rp = s[t] - v + boffv;
        rowptr[i] = rp;
        // offsets: hist[r][c][li] -> running cursor
        int r = i / NRG, li = i - r * NRG;
        int* hp = hist + ((size_t)r * CHK) * NRG + li;
        int run = rp;
#pragma unroll
        for (int c = 0; c < CHK; c++) {
            int hv = hp[(size_t)c * NRG];
            hp[(size_t)c * NRG] = run;
            run += hv;
        }
        // pad slots -> zero-row N
        for (int e = rp + cv; e < rp + v; e++) col[e] = N;
    }
}

__global__ __launch_bounds__(256) void fill2_k(
    const unsigned* __restrict__ bucket, const int* __restrict__ bstart,
    const int* __restrict__ hist, int* __restrict__ col) {
    __shared__ int cur[NRG];
    int b = blockIdx.x, r = b & 63, c2 = b >> 6, t = threadIdx.x;
    const int* hp = hist + ((size_t)r * CHK + c2) * NRG;
    for (int i = t; i < NRG; i += 256) cur[i] = hp[i];
    int s0 = bstart[r], s1 = bstart[r + 1];
    int ec = (s1 - s0 + CHK - 1) / CHK;
    int e0 = s0 + c2 * ec, e1 = min(s1, e0 + ec);
    __syncthreads();
    for (int e = e0 + t; e < e1; e += 256) {
        unsigned v = __builtin_nontemporal_load(bucket + e);
        int slot = atomicAdd(&cur[v >> 17], 1);   // LDS atomic
        col[slot] = (int)(v & 0x1FFFFu);
    }
}

// ---------------- weight prep: fp32 W[K][OUT] -> bf16 W^T[OUT][K] ----------------
// Layout: W1t(16384) W2t(16384) W3t(8192) Wh1t(16384: Wa1 rows 0..127,
// Wc1 rows 128..255, K=64) Wa2t(8192) Wc2t(8192)

__global__ __launch_bounds__(256) void prep_w_k(
    const float* __restrict__ W1, const float* __restrict__ W2,
    const float* __restrict__ W3, const float* __restrict__ Wa1,
    const float* __restrict__ Wc1, const float* __restrict__ Wa2,
    const float* __restrict__ Wc2, unsigned short* __restrict__ wt) {
    int i = blockIdx.x * 256 + threadIdx.x;   // 0..73727
    const float* W; int off, K, OUT;
    if (i < 16384)      { W = W1;  off = 0;     K = 128; OUT = 128; }
    else if (i < 32768) { W = W2;  off = 16384; K = 128; OUT = 128; }
    else if (i < 40960) { W = W3;  off = 32768; K = 128; OUT = 64; }
    else if (i < 49152) { W = Wa1; off = 40960; K = 64;  OUT = 128; }
    else if (i < 57344) { W = Wc1; off = 49152; K = 64;  OUT = 128; }
    else if (i < 65536) { W = Wa2; off = 57344; K = 128; OUT = 64; }
    else                { W = Wc2; off = 65536; K = 128; OUT = 64; }
    int j = i - off, k = j / OUT, n = j - k * OUT;
    wt[off + n * K + k] = f2b(W[j]);
}

// ---------------- gemm2: weights-stationary grid-stride MFMA GEMM ----------------
// EPI 0: fp8(acc * dinv[row] * S), unguarded rows (zero pad-row at N)

template <int K, int OUT, int EPI, bool AF32>
__global__ __launch_bounds__(256) void gemm2_k(
    const void* __restrict__ Xv, int ldx, const unsigned short* __restrict__ Wt,
    const float* __restrict__ sb, const float* __restrict__ w3b,
    const float* __restrict__ b3, void* __restrict__ Yv, int N, int NT) {
    constexpr int LDK = K + 8;
    __shared__ __align__(16) unsigned short Bs[OUT * LDK];
    __shared__ __align__(16) unsigned short As[64 * LDK];
    int t = threadIdx.x;

    // stage B once per block (visible after first in-loop barrier)
    for (int g = t; g < OUT * (K / 8); g += 256) {
        int r = g / (K / 8), q = g - r * (K / 8);
        *(uint4*)&Bs[r * LDK + q * 8] = *(const uint4*)(Wt + r * K + q * 8);
    }

    int wv = t >> 6, lane = t & 63;
    int lm = lane & 15, lq = lane >> 4;
    constexpr int CT = OUT / 16;

    for (int tile = blockIdx.x; tile < NT; tile += gridDim.x) {
        int rowBase = tile * 64;

        // stage A tile
        if constexpr (AF32) {
            const float* X = (const float*)Xv;
            for (int g = t; g < 64 * (K / 8); g += 256) {
                int r = g / (K / 8), q = g - r * (K / 8);
                int gr = rowBase + r;
                unsigned short us[8];
                if (gr < N) {
                    float4 v0 = *(const float4*)(X + (size_t)gr * ldx + q * 8);
                    float4 v1 = *(const float4*)(X + (size_t)gr * ldx + q * 8 + 4);
                    us[0] = f2b(v0.x); us[1] = f2b(v0.y); us[2] = f2b(v0.z); us[3] = f2b(v0.w);
                    us[4] = f2b(v1.x); us[5] = f2b(v1.y); us[6] = f2b(v1.z); us[7] = f2b(v1.w);
                } else {
#pragma unroll
                    for (int j = 0; j < 8; j++) us[j] = 0;
                }
                *(uint4*)&As[r * LDK + q * 8] = *(uint4*)us;
            }
        } else {
            const unsigned short* X = (const unsigned short*)Xv;
            for (int g = t; g < 64 * (K / 8); g += 256) {
                int r = g / (K / 8), q = g - r * (K / 8);
                int gr = rowBase + r;
                uint4 v = make_uint4(0, 0, 0, 0);
                if (gr < N) v = *(const uint4*)(X + (size_t)gr * ldx + q * 8);
                *(uint4*)&As[r * LDK + q * 8] = v;
            }
        }
        __syncthreads();

        f32x4 acc[CT];
#pragma unroll
        for (int c = 0; c < CT; c++) acc[c] = (f32x4){0.f, 0.f, 0.f, 0.f};

        const unsigned short* arow = &As[(wv * 16 + lm) * LDK + lq * 8];
#pragma unroll
        for (int kt = 0; kt < K / 32; kt++) {
            bf16x8 a = *(const bf16x8*)(arow + kt * 32);
#pragma unroll
            for (int c = 0; c < CT; c++) {
                bf16x8 b = *(const bf16x8*)&Bs[(c * 16 + lm) * LDK + kt * 32 + lq * 8];
                acc[c] = __builtin_amdgcn_mfma_f32_16x16x32_bf16(a, b, acc[c], 0, 0, 0);
            }
        }

        // epilogue: C/D layout col=lane&15, row=(lane>>4)*4+reg [m89/m91]
        int r0 = rowBase + wv * 16 + lq * 4;
        if constexpr (EPI == 0) {
#pragma unroll
            for (int r = 0; r < 4; r++) {
                int gr = r0 + r;
                float scale = (gr < N) ? sb[gr] * S_FP8 : 0.f;
#pragma unroll
                for (int c = 0; c < CT; c++) {
                    int colg = c * 16 + lm;
                    ((unsigned char*)Yv)[(size_t)gr * OUT + colg] = f2fp8(acc[c][r] * scale);
                }
            }
        }
        __syncthreads();   // protect As before next tile's staging
    }
}

// ---------------- aggregation (one node per wave; R9-proven) ----------------

template <bool RELU>
__global__ __launch_bounds__(256) void agg128_k(
    const unsigned char* __restrict__ H,   // [(Npad+64),128] fp8, rows>=N zero
    const int* __restrict__ rowptr, const int* __restrict__ col,
    const float* __restrict__ dinv, const float* __restrict__ bias,
    unsigned short* __restrict__ Y, int N, int Ecap) {
    int tid = threadIdx.x;
    int node = blockIdx.x * 4 + (tid >> 6);
    if (node >= N) return;
    int lane = tid & 63;
    int grp = lane >> 4;
    int li8 = (lane & 15) * 8;

    f32x2 a01 = {0.f, 0.f}, a23 = {0.f, 0.f}, a45 = {0.f, 0.f}, a67 = {0.f, 0.f};
    if (grp == 0) {
        uint2 u = *(const uint2*)(H + (size_t)node * 128 + li8);
        acc8(u, a01, a23, a45, a67);
    }

    int start = rowptr[node], end = rowptr[node + 1];
    for (int e0 = start; e0 < end; e0 += 64) {
        int cv = col[min(e0 + lane, Ecap - 1)];
        int quads = min(64, end - e0) >> 2;
        for (int q = 0; q < quads; q += 2) {
            int s0 = __shfl(cv, 4 * q + grp, 64);
            int s1 = __shfl(cv, 4 * q + 4 + grp, 64);
            uint2 u0 = *(const uint2*)(H + (size_t)s0 * 128 + li8);
            uint2 u1 = *(const uint2*)(H + (size_t)s1 * 128 + li8);
            acc8(u0, a01, a23, a45, a67);
            acc8(u1, a01, a23, a45, a67);
        }
    }

#pragma unroll
    for (int w = 16; w < 64; w <<= 1) {
        a01[0] += __shfl_xor(a01[0], w, 64); a01[1] += __shfl_xor(a01[1], w, 64);
        a23[0] += __shfl_xor(a23[0], w, 64); a23[1] += __shfl_xor(a23[1], w, 64);
        a45[0] += __shfl_xor(a45[0], w, 64); a45[1] += __shfl_xor(a45[1], w, 64);
        a67[0] += __shfl_xor(a67[0], w, 64); a67[1] += __shfl_xor(a67[1], w, 64);
    }

    if (grp == 0) {
        float dv = dinv[node] * S_FP8_INV;
        float4 b0 = *(const float4*)(bias + li8);
        float4 b1 = *(const float4*)(bias + li8 + 4);
        float o0 = a01[0] * dv + b0.x, o1 = a01[1] * dv + b0.y;
        float o2 = a23[0] * dv + b0.z, o3 = a23[1] * dv + b0.w;
        float o4 = a45[0] * dv + b1.x, o5 = a45[1] * dv + b1.y;
        float o6 = a67[0] * dv + b1.z, o7 = a67[1] * dv + b1.w;
        if (RELU) {
            o0 = fmaxf(o0, 0.f); o1 = fmaxf(o1, 0.f); o2 = fmaxf(o2, 0.f); o3 = fmaxf(o3, 0.f);
            o4 = fmaxf(o4, 0.f); o5 = fmaxf(o5, 0.f); o6 = fmaxf(o6, 0.f); o7 = fmaxf(o7, 0.f);
        }
        unsigned short us[8] = {f2b(o0), f2b(o1), f2b(o2), f2b(o3),
                                f2b(o4), f2b(o5), f2b(o6), f2b(o7)};
        *(uint4*)(Y + (size_t)node * 128 + li8) = *(uint4*)us;
    }
}

__global__ __launch_bounds__(256) void agg64_k(
    const unsigned char* __restrict__ H,   // [(Npad+64),64] fp8, rows>=N zero
    const int* __restrict__ rowptr, const int* __restrict__ col,
    const float* __restrict__ dinv, const float* __restrict__ bias,
    unsigned short* __restrict__ Y, int N, int Ecap) {
    int tid = threadIdx.x;
    int node = blockIdx.x * 4 + (tid >> 6);
    if (node >= N) return;
    int lane = tid & 63;
    int grp = lane >> 3;
    int li8 = (lane & 7) * 8;

    f32x2 a01 = {0.f, 0.f}, a23 = {0.f, 0.f}, a45 = {0.f, 0.f}, a67 = {0.f, 0.f};
    if (grp == 0) {
        uint2 u = *(const uint2*)(H + (size_t)node * 64 + li8);
        acc8(u, a01, a23, a45, a67);
    }

    int start = rowptr[node], end = rowptr[node + 1];
    for (int e0 = start; e0 < end; e0 += 64) {
        int cv = col[min(e0 + lane, Ecap - 1)];
        int octs = min(64, end - e0) >> 3;
        int o = 0;
        for (; o + 2 <= octs; o += 2) {
            int s0 = __shfl(cv, 8 * o + grp, 64);
            int s1 = __shfl(cv, 8 * o + 8 + grp, 64);
            uint2 u0 = *(const uint2*)(H + (size_t)s0 * 64 + li8);
            uint2 u1 = *(const uint2*)(H + (size_t)s1 * 64 + li8);
            acc8(u0, a01, a23, a45, a67);
            acc8(u1, a01, a23, a45, a67);
        }
        if (o < octs) {
            int s0 = __shfl(cv, 8 * o + grp, 64);
            uint2 u0 = *(const uint2*)(H + (size_t)s0 * 64 + li8);
            acc8(u0, a01, a23, a45, a67);
        }
    }

#pragma unroll
    for (int w = 8; w < 64; w <<= 1) {
        a01[0] += __shfl_xor(a01[0], w, 64); a01[1] += __shfl_xor(a01[1], w, 64);
        a23[0] += __shfl_xor(a23[0], w, 64); a23[1] += __shfl_xor(a23[1], w, 64);
        a45[0] += __shfl_xor(a45[0], w, 64); a45[1] += __shfl_xor(a45[1], w, 64);
        a67[0] += __shfl_xor(a67[0], w, 64); a67[1] += __shfl_xor(a67[1], w, 64);
    }

    if (grp == 0) {
        float dv = dinv[node] * S_FP8_INV;
        float4 b0 = *(const float4*)(bias + li8);
        float4 b1 = *(const float4*)(bias + li8 + 4);
        unsigned short us[8] = {
            f2b(a01[0] * dv + b0.x), f2b(a01[1] * dv + b0.y),
            f2b(a23[0] * dv + b0.z), f2b(a23[1] * dv + b0.w),
            f2b(a45[0] * dv + b1.x), f2b(a45[1] * dv + b1.y),
            f2b(a67[0] * dv + b1.z), f2b(a67[1] * dv + b1.w)};
        *(uint4*)(Y + (size_t)node * 64 + li8) = *(uint4*)us;
    }
}

// ---------------- fused actor/critic heads (R12-proven pair) ----------------
// EPI 2: actor  (L1 relu -> L2 relu -> logits -> softmax -> out[0..8))
// EPI 3: critic (L1 relu -> L2 relu -> value -> out[8])
// Weights staged once per block; per 64-row tile each wave handles its own
// 16 rows end-to-end through wave-private LDS (no per-tile barriers).

template <int EPI>
__global__ __launch_bounds__(256) void heads_k(
    const unsigned short* __restrict__ h3,   // [N,64] bf16
    const unsigned short* __restrict__ W1t,  // [128][64] bf16 (head L1)
    const float* __restrict__ b1v,           // [128]
    const unsigned short* __restrict__ W2t,  // [64][128] bf16 (head L2)
    const float* __restrict__ b2v,           // [64]
    const float* __restrict__ w3,            // Wa3 [64][8] / Wc3 [64][1] fp32
    const float* __restrict__ b3v,
    float* __restrict__ out, int N, int NT) {
    constexpr int LD64 = 72, LD128 = 136;
    __shared__ __align__(16) unsigned short Bs1[128 * LD64];   // 18.4KB
    __shared__ __align__(16) unsigned short Bs2[64 * LD128];   // 17.4KB
    __shared__ __align__(16) unsigned short As[4 * 16 * LD64]; //  9.2KB
    __shared__ __align__(16) unsigned short A1[4 * 16 * LD128];// 17.4KB
    int t = threadIdx.x, wv = t >> 6, lane = t & 63;
    int lm = lane & 15, lq = lane >> 4;

    // stage head weights once per block
    for (int g = t; g < 128 * 8; g += 256) {
        int r = g >> 3, q = g & 7;
        *(uint4*)&Bs1[r * LD64 + q * 8] = *(const uint4*)(W1t + r * 64 + q * 8);
    }
    for (int g = t; g < 64 * 16; g += 256) {
        int r = g >> 4, q = g & 15;
        *(uint4*)&Bs2[r * LD128 + q * 8] = *(const uint4*)(W2t + r * 128 + q * 8);
    }
    __syncthreads();

    unsigned short* Asw = &As[wv * 16 * LD64];
    unsigned short* A1w = &A1[wv * 16 * LD128];

    for (int tile = blockIdx.x; tile < NT; tile += gridDim.x) {
        int rowBase = tile * 64 + wv * 16;

        // stage wave's 16 h3 rows
        for (int g = lane; g < 16 * 8; g += 64) {
            int r = g >> 3, q = g & 7;
            int gr = rowBase + r;
            uint4 v = make_uint4(0, 0, 0, 0);
            if (gr < N) v = *(const uint4*)(h3 + (size_t)gr * 64 + q * 8);
            *(uint4*)&Asw[r * LD64 + q * 8] = v;
        }

        // L1: 16x128, K=64
        f32x4 acc1[8];
#pragma unroll
        for (int c = 0; c < 8; c++) acc1[c] = (f32x4){0.f, 0.f, 0.f, 0.f};
        const unsigned short* arow = &Asw[lm * LD64 + lq * 8];
#pragma unroll
        for (int kt = 0; kt < 2; kt++) {
            bf16x8 a = *(const bf16x8*)(arow + kt * 32);
#pragma unroll
            for (int c = 0; c < 8; c++) {
                bf16x8 b = *(const bf16x8*)&Bs1[(c * 16 + lm) * LD64 + kt * 32 + lq * 8];
                acc1[c] = __builtin_amdgcn_mfma_f32_16x16x32_bf16(a, b, acc1[c], 0, 0, 0);
            }
        }
        // relu + bf16 -> wave-private A1
#pragma unroll
        for (int r = 0; r < 4; r++) {
            int lr = lq * 4 + r;
#pragma unroll
            for (int c = 0; c < 8; c++) {
                int colg = c * 16 + lm;
                float v = fmaxf(acc1[c][r] + b1v[colg], 0.f);
                A1w[lr * LD128 + colg] = f2b(v);
            }
        }

        // L2: 16x64, K=128
        f32x4 acc[4];
#pragma unroll
        for (int c = 0; c < 4; c++) acc[c] = (f32x4){0.f, 0.f, 0.f, 0.f};
        const unsigned short* arow2 = &A1w[lm * LD128 + lq * 8];
#pragma unroll
        for (int kt = 0; kt < 4; kt++) {
            bf16x8 a = *(const bf16x8*)(arow2 + kt * 32);
#pragma unroll
            for (int c = 0; c < 4; c++) {
                bf16x8 b = *(const bf16x8*)&Bs2[(c * 16 + lm) * LD128 + kt * 32 + lq * 8];
                acc[c] = __builtin_amdgcn_mfma_f32_16x16x32_bf16(a, b, acc[c], 0, 0, 0);
            }
        }

        int r0 = rowBase + lq * 4;
        if constexpr (EPI == 2) {
            float l[4][8];
#pragma unroll
            for (int r = 0; r < 4; r++)
#pragma unroll
                for (int a = 0; a < 8; a++) l[r][a] = 0.f;
#pragma unroll
            for (int c = 0; c < 4; c++) {
                int colg = c * 16 + lm;
#pragma unroll
                for (int r = 0; r < 4; r++) {
                    float v = fmaxf(acc[c][r] + b2v[colg], 0.f);
#pragma unroll
                    for (int a = 0; a < 8; a++)
                        l[r][a] = fmaf(v, w3[colg * 8 + a], l[r][a]);
                }
            }
#pragma unroll
            for (int w = 1; w < 16; w <<= 1)
#pragma unroll
                for (int r = 0; r < 4; r++)
#pragma unroll
                    for (int a = 0; a < 8; a++)
                        l[r][a] += __shfl_xor(l[r][a], w, 64);
            if (lm < 8) {
#pragma unroll
                for (int r = 0; r < 4; r++) {
                    int gr = r0 + r;
                    if (gr < N) {
                        float lg[8], m = -1e30f;
#pragma unroll
                        for (int a = 0; a < 8; a++) { lg[a] = l[r][a] + b3v[a]; m = fmaxf(m, lg[a]); }
                        float sum = 0.f;
#pragma unroll
                        for (int a = 0; a < 8; a++) { lg[a] = expf(lg[a] - m); sum += lg[a]; }
                        out[(size_t)gr * 9 + lm] = lg[lm] / sum;
                    }
                }
            }
        } else {   // EPI == 3: critic value
            float lv[4] = {0.f, 0.f, 0.f, 0.f};
#pragma unroll
            for (int c = 0; c < 4; c++) {
                int colg = c * 16 + lm;
#pragma unroll
                for (int r = 0; r < 4; r++) {
                    float v = fmaxf(acc[c][r] + b2v[colg], 0.f);
                    lv[r] = fmaf(v, w3[colg], lv[r]);
                }
            }
#pragma unroll
            for (int w = 1; w < 16; w <<= 1)
#pragma unroll
                for (int r = 0; r < 4; r++) lv[r] += __shfl_xor(lv[r], w, 64);
            if (lm == 0) {
#pragma unroll
                for (int r = 0; r < 4; r++) {
                    int gr = r0 + r;
                    if (gr < N) out[(size_t)gr * 9 + 8] = lv[r] + b3v[0];
                }
            }
        }
    }
}

// ---------------- launch ----------------

extern "C" void kernel_launch(void* const* d_in, const int* in_sizes, int n_in,
                              void* d_out, int out_size, void* d_ws, size_t ws_size,
                              hipStream_t stream) {
    const float* x   = (const float*)d_in[0];
    const int*   ei  = (const int*)d_in[1];
    const float* W1  = (const float*)d_in[2];  const float* b1  = (const float*)d_in[3];
    const float* W2  = (const float*)d_in[4];  const float* b2  = (const float*)d_in[5];
    const float* W3  = (const float*)d_in[6];  const float* b3  = (const float*)d_in[7];
    const float* Wa1 = (const float*)d_in[8];  const float* ba1 = (const float*)d_in[9];
    const float* Wa2 = (const float*)d_in[10]; const float* ba2 = (const float*)d_in[11];
    const float* Wa3 = (const float*)d_in[12]; const float* ba3 = (const float*)d_in[13];
    const float* Wc1 = (const float*)d_in[14]; const float* bc1 = (const float*)d_in[15];
    const float* Wc2 = (const float*)d_in[16]; const float* bc2 = (const float*)d_in[17];
    const float* Wc3 = (const float*)d_in[18]; const float* bc3 = (const float*)d_in[19];
    float* out = (float*)d_out;

    const int N = in_sizes[0] / 128;     // 100000
    const int E = in_sizes[1] / 2;       // 3200000
    const int* src = ei;
    const int* dst = ei + E;
    const int Ecap = E + 8 * N;          // padded-CSR capacity
    const int Npad = ((N + 63) / 64) * 64;
    const int NT   = (N + 63) / 64;      // 1563 row tiles

    // workspace layout
    size_t off = 0;
    auto take = [&](size_t bytes) { size_t o = off; off = WS_ALIGN(off + bytes); return o; };
    char* ws = (char*)d_ws;
    unsigned short* h3     = (unsigned short*)(ws + take((size_t)N * 64 * 2));       // 12.8MB
    unsigned short* h      = (unsigned short*)(ws + take((size_t)N * 128 * 2));      // 25.6MB
    unsigned char*  hpr8   = (unsigned char*) (ws + take((size_t)(Npad + 64) * 128));// 12.8MB
    int*            col    = (int*)(ws + take((size_t)Ecap * 4));                    // 16MB
    unsigned short* wt     = (unsigned short*)(ws + take(73728 * 2));
    float* dinv   = (float*)(ws + take((size_t)(N + 64) * 4));
    int*   cnt    = (int*)  (ws + take((size_t)N * 4));
    int*   rowptr = (int*)  (ws + take((size_t)(N + 1) * 4));
    int*   bcnt   = (int*)  (ws + take((size_t)RNG * NB * 4));
    int*   base   = (int*)  (ws + take((size_t)RNG * NB * 4));
    int*   rtot   = (int*)  (ws + take(RNG * 4));
    int*   bstart = (int*)  (ws + take((RNG + 1) * 4));
    int*   bsum   = (int*)  (ws + take(512 * 4));
    // aliases: bucket (12.8MB) on h [h written first by agg128, after fill2];
    // hist (6.4MB) on h3 [h3 written only by agg64, after fill2].
    unsigned* bucket = (unsigned*)h;
    int* hist = (int*)h3;
    (void)ws_size; (void)n_in; (void)out_size;

    const int nb  = (N + 255) / 256;     // 391
    const int GG128 = 768;               // gemm2<128,128>: 3 blocks/CU by LDS
    const int GG64  = 1024;              // gemm2<128,64>: 4 blocks/CU by LDS
    const int GGH   = 512;               // heads: 62.4KB LDS -> 2 blocks/CU

    prep_w_k<<<288, 256, 0, stream>>>(W1, W2, W3, Wa1, Wc1, Wa2, Wc2, wt);
    const unsigned short* W1t  = wt;
    const unsigned short* W2t  = wt + 16384;
    const unsigned short* W3t  = wt + 32768;
    const unsigned short* Wh1t = wt + 40960;   // [256][64] concat actor|critic L1
    const unsigned short* Wa2t = wt + 57344;
    const unsigned short* Wc2t = wt + 65536;

    // CSR build
    bucket_count_k<<<NB, 256, 0, stream>>>(dst, bcnt, E);
    rsum_k<<<RNG, 256, 0, stream>>>(bcnt, base, rtot);
    rstart_k<<<1, 64, 0, stream>>>(rtot, bstart, E);
    bucket_scatter_k<<<NB, 256, 0, stream>>>(src, dst, base, bstart, bucket, E);
    hist_bucket_k<<<RNG * CHK, 256, 0, stream>>>(bucket, bstart, hist);
    sum_hist_dinv_k<<<nb, 256, 0, stream>>>(hist, cnt, dinv, bsum, N);
    scan_off_pad_k<<<nb, 256, 0, stream>>>(cnt, bsum, rowptr, hist, col, N);
    fill2_k<<<RNG * CHK, 256, 0, stream>>>(bucket, bstart, hist, col);

    // GCN layer 1..3 (gemm -> fp8 -> gather-agg)
    gemm2_k<128, 128, 0, true><<<GG128, 256, 0, stream>>>(
        x, 128, W1t, dinv, nullptr, nullptr, hpr8, N, NT);
    agg128_k<true><<<(N + 3) / 4, 256, 0, stream>>>(hpr8, rowptr, col, dinv, b1, h, N, Ecap);
    gemm2_k<128, 128, 0, false><<<GG128, 256, 0, stream>>>(
        h, 128, W2t, dinv, nullptr, nullptr, hpr8, N, NT);
    agg128_k<true><<<(N + 3) / 4, 256, 0, stream>>>(hpr8, rowptr, col, dinv, b2, h, N, Ecap);
    gemm2_k<128, 64, 0, false><<<GG64, 256, 0, stream>>>(
        h, 128, W3t, dinv, nullptr, nullptr, hpr8, N, NT);
    agg64_k<<<(N + 3) / 4, 256, 0, stream>>>(hpr8, rowptr, col, dinv, b3, h3, N, Ecap);

    // fused heads (h3 -> out), actor then critic
    heads_k<2><<<GGH, 256, 0, stream>>>(h3, Wh1t, ba1, Wa2t, ba2, Wa3, ba3, out, N, NT);
    heads_k<3><<<GGH, 256, 0, stream>>>(h3, Wh1t + 128 * 64, bc1, Wc2t, bc2, Wc3, bc3, out, N, NT);
}

// Round 6
// 462.652 us; speedup vs baseline: 1.0979x; 1.0058x over previous
//
#include <hip/hip_runtime.h>
#include <hip/hip_bf16.h>
#include <math.h>

// ---------------------------------------------------------------------------
// FederatedPPOAgent: 3x GCNConv (N=100k, E=3.2M, D=128) + actor/critic MLPs.
//
// R15 changes vs R14 (launch-count trimming; gather path untouched):
//  - headsB_k: actor+critic in ONE launch via BLOCK specialization (blocks
//    <GH actor, >=GH critic). Each block runs one path only -> VGPR = max of
//    single-head paths (unlike R13's merged-body 216-VGPR disaster); B still
//    LDS-staged. Two serial ~14us kernels -> one ~16us concurrent kernel.
//  - rstart_k DELETED: bucket_scatter/hist_bucket/fill2 compute bstart
//    prefix from rtot inline (64 L2-hot ints per block).
//  - prep_w_k folded into bucket_count_k (73728 elems over 262144 threads).
//  - 19 -> 16 dispatches. agg128/agg64/gemm2 unchanged (gather at HW
//    ceiling: 66us, 2.9 TB/s, 162MB FETCH).
// ---------------------------------------------------------------------------

#define WS_ALIGN(x) (((x) + 255) & ~(size_t)255)

constexpr int RNG  = 64;        // node ranges
constexpr int NRG  = 1563;      // nodes per range (64*1563 >= 100000)
constexpr int NB   = 1024;      // bucket-phase blocks
constexpr int CHK  = 16;        // per-range fill chunks

constexpr float S_FP8     = 64.0f;
constexpr float S_FP8_INV = 1.0f / 64.0f;

using bf16x8 = __attribute__((ext_vector_type(8))) short;
using f32x4  = __attribute__((ext_vector_type(4))) float;
using f32x2  = __attribute__((ext_vector_type(2))) float;

__device__ __forceinline__ float b2f(unsigned short u) {
    return __uint_as_float(((unsigned int)u) << 16);
}
__device__ __forceinline__ unsigned short f2b(float f) {
    __hip_bfloat16 hb = __float2bfloat16(f);
    return *(unsigned short*)&hb;
}
__device__ __forceinline__ unsigned char f2fp8(float f) {
    return (unsigned char)(__builtin_amdgcn_cvt_pk_fp8_f32(f, f, 0, false) & 0xff);
}
__device__ __forceinline__ int pad8(int v) { return (v + 7) & ~7; }

// 8 fp8 (uint2) -> 4 packed-f32 accumulators
__device__ __forceinline__ void acc8(uint2 u, f32x2& a01, f32x2& a23,
                                     f32x2& a45, f32x2& a67) {
    a01 += __builtin_amdgcn_cvt_pk_f32_fp8((int)u.x, false);
    a23 += __builtin_amdgcn_cvt_pk_f32_fp8((int)u.x, true);
    a45 += __builtin_amdgcn_cvt_pk_f32_fp8((int)u.y, false);
    a67 += __builtin_amdgcn_cvt_pk_f32_fp8((int)u.y, true);
}

// ---------------- CSR build ----------------

// + folded weight prep: fp32 W[K][OUT] -> bf16 W^T[OUT][K]
// Layout: W1t(16384) W2t(16384) W3t(8192) Wh1t(16384: Wa1 rows 0..127,
// Wc1 rows 128..255, K=64) Wa2t(8192) Wc2t(8192)
__global__ __launch_bounds__(256) void bucket_count_k(
    const int* __restrict__ dst, int* __restrict__ bcnt, int E,
    const float* __restrict__ W1, const float* __restrict__ W2,
    const float* __restrict__ W3, const float* __restrict__ Wa1,
    const float* __restrict__ Wc1, const float* __restrict__ Wa2,
    const float* __restrict__ Wc2, unsigned short* __restrict__ wt) {
    __shared__ int c64[RNG];
    int b = blockIdx.x, t = threadIdx.x;

    // folded prep_w (73728 elems; grid has 262144 threads)
    int gi = b * 256 + t;
    if (gi < 73728) {
        const float* W; int off, K, OUT;
        if (gi < 16384)      { W = W1;  off = 0;     K = 128; OUT = 128; }
        else if (gi < 32768) { W = W2;  off = 16384; K = 128; OUT = 128; }
        else if (gi < 40960) { W = W3;  off = 32768; K = 128; OUT = 64; }
        else if (gi < 49152) { W = Wa1; off = 40960; K = 64;  OUT = 128; }
        else if (gi < 57344) { W = Wc1; off = 49152; K = 64;  OUT = 128; }
        else if (gi < 65536) { W = Wa2; off = 57344; K = 128; OUT = 64; }
        else                 { W = Wc2; off = 65536; K = 128; OUT = 64; }
        int j = gi - off, k = j / OUT, n = j - k * OUT;
        wt[off + n * K + k] = f2b(W[j]);
    }

    if (t < RNG) c64[t] = 0;
    __syncthreads();
    int ec = (E + NB - 1) / NB;
    int e0 = b * ec, e1 = min(E, e0 + ec);
    for (int e = e0 + t; e < e1; e += 256) {
        int d = __builtin_nontemporal_load(dst + e);
        atomicAdd(&c64[d / NRG], 1);
    }
    __syncthreads();
    if (t < RNG) bcnt[t * NB + b] = c64[t];
}

// block r: exclusive scan of bcnt[r][0..NB) -> base, total -> rtot[r]
__global__ __launch_bounds__(256) void rsum_k(
    const int* __restrict__ bcnt, int* __restrict__ base, int* __restrict__ rtot) {
    __shared__ int s[256];
    int r = blockIdx.x, t = threadIdx.x;
    const int* row = bcnt + (size_t)r * NB;
    int v[4], loc = 0;
#pragma unroll
    for (int j = 0; j < 4; j++) { v[j] = row[t * 4 + j]; loc += v[j]; }
    s[t] = loc;
    __syncthreads();
    for (int d = 1; d < 256; d <<= 1) {
        int x = (t >= d) ? s[t - d] : 0;
        __syncthreads();
        s[t] += x;
        __syncthreads();
    }
    int run = s[t] - loc;   // exclusive
    int* bp = base + (size_t)r * NB + t * 4;
#pragma unroll
    for (int j = 0; j < 4; j++) { bp[j] = run; run += v[j]; }
    if (t == 255) rtot[r] = s[255];
}

__global__ __launch_bounds__(256) void bucket_scatter_k(
    const int* __restrict__ src, const int* __restrict__ dst,
    const int* __restrict__ base, const int* __restrict__ rtot,
    unsigned* __restrict__ bucket, int E) {
    __shared__ int cur[RNG];
    __shared__ int rt[RNG];
    int b = blockIdx.x, t = threadIdx.x;
    if (t < RNG) rt[t] = rtot[t];
    __syncthreads();
    if (t < RNG) {
        int run = 0;
        for (int j = 0; j < t; j++) run += rt[j];   // bstart[t] inline
        cur[t] = run + base[(size_t)t * NB + b];
    }
    __syncthreads();
    int ec = (E + NB - 1) / NB;
    int e0 = b * ec, e1 = min(E, e0 + ec);
    for (int e = e0 + t; e < e1; e += 256) {
        int d = __builtin_nontemporal_load(dst + e);
        int sv = __builtin_nontemporal_load(src + e);
        int r = d / NRG;
        int pos = atomicAdd(&cur[r], 1);
        bucket[pos] = ((unsigned)(d - r * NRG) << 17) | (unsigned)sv;
    }
}

__global__ __launch_bounds__(256) void hist_bucket_k(
    const unsigned* __restrict__ bucket, const int* __restrict__ rtot,
    int* __restrict__ hist) {
    __shared__ int h[NRG];
    __shared__ int ss[2];
    int b = blockIdx.x, r = b & 63, c2 = b >> 6, t = threadIdx.x;
    for (int i = t; i < NRG; i += 256) h[i] = 0;
    if (t == 0) {
        int run = 0;
        for (int j = 0; j < r; j++) run += rtot[j];
        ss[0] = run; ss[1] = run + rtot[r];
    }
    __syncthreads();
    int s0 = ss[0], s1 = ss[1];
    int ec = (s1 - s0 + CHK - 1) / CHK;
    int e0 = s0 + c2 * ec, e1 = min(s1, e0 + ec);
    for (int e = e0 + t; e < e1; e += 256) {
        unsigned v = __builtin_nontemporal_load(bucket + e);
        atomicAdd(&h[v >> 17], 1);
    }
    __syncthreads();
    int* out = hist + ((size_t)r * CHK + c2) * NRG;
    for (int i = t; i < NRG; i += 256) out[i] = h[i];
}

// per-node degree + dinv + per-block padded-count sum (chunk_sum folded in)
__global__ __launch_bounds__(256) void sum_hist_dinv_k(
    const int* __restrict__ hist, int* __restrict__ cnt,
    float* __restrict__ dinv, int* __restrict__ bsum, int N) {
    __shared__ int sd[256];
    int t = threadIdx.x;
    int i = blockIdx.x * 256 + t;
    int s = 0;
    if (i < N) {
        int r = i / NRG, li = i - r * NRG;
        const int* hp = hist + ((size_t)r * CHK) * NRG + li;
#pragma unroll
        for (int c = 0; c < CHK; c++) s += hp[(size_t)c * NRG];
        cnt[i] = s;
        dinv[i] = rsqrtf((float)s + 1.0f);   // +1: self loop
    }
    sd[t] = (i < N) ? pad8(s) : 0;
    __syncthreads();
    for (int d = 128; d > 0; d >>= 1) {
        if (t < d) sd[t] += sd[t + d];
        __syncthreads();
    }
    if (t == 0) bsum[blockIdx.x] = sd[0];
}

// scan_final + boff-from-bsum (scan_mid folded) + offsets + pad_col
__global__ void scan_off_pad_k(const int* __restrict__ cnt, const int* __restrict__ bsum,
                               int* __restrict__ rowptr, int* __restrict__ hist,
                               int* __restrict__ col, int N) {
    __shared__ int s[256];
    int t = threadIdx.x, b = blockIdx.x;

    // boff = sum of bsum[j] for j < b (bsum is L2-hot, <=391 ints)
    int part = 0;
    for (int j = t; j < b; j += 256) part += bsum[j];
    s[t] = part;
    __syncthreads();
    for (int d = 128; d > 0; d >>= 1) {
        if (t < d) s[t] += s[t + d];
        __syncthreads();
    }
    int boffv = s[0];
    __syncthreads();

    int i = b * 256 + t;
    int cv = (i < N) ? cnt[i] : 0;
    int v = pad8(cv);
    if (i >= N) v = 0;
    s[t] = v;
    __syncthreads();
    for (int d = 1; d < 256; d <<= 1) {
        int x = (t >= d) ? s[t - d] : 0;
        __syncthreads();
        s[t] += x;
        __syncthreads();
    }
    if (b == (int)gridDim.x - 1 && t == 255) rowptr[N] = boffv + s[255];
    if (i < N) {
        int rp = s[t] - v + boffv;
        rowptr[i] = rp;
        // offsets: hist[r][c][li] -> running cursor
        int r = i / NRG, li = i - r * NRG;
        int* hp = hist + ((size_t)r * CHK) * NRG + li;
        int run = rp;
#pragma unroll
        for (int c = 0; c < CHK; c++) {
            int hv = hp[(size_t)c * NRG];
            hp[(size_t)c * NRG] = run;
            run += hv;
        }
        // pad slots -> zero-row N
        for (int e = rp + cv; e < rp + v; e++) col[e] = N;
    }
}

__global__ __launch_bounds__(256) void fill2_k(
    const unsigned* __restrict__ bucket, const int* __restrict__ rtot,
    const int* __restrict__ hist, int* __restrict__ col) {
    __shared__ int cur[NRG];
    __shared__ int ss[2];
    int b = blockIdx.x, r = b & 63, c2 = b >> 6, t = threadIdx.x;
    const int* hp = hist + ((size_t)r * CHK + c2) * NRG;
    for (int i = t; i < NRG; i += 256) cur[i] = hp[i];
    if (t == 0) {
        int run = 0;
        for (int j = 0; j < r; j++) run += rtot[j];
        ss[0] = run; ss[1] = run + rtot[r];
    }
    __syncthreads();
    int s0 = ss[0], s1 = ss[1];
    int ec = (s1 - s0 + CHK - 1) / CHK;
    int e0 = s0 + c2 * ec, e1 = min(s1, e0 + ec);
    for (int e = e0 + t; e < e1; e += 256) {
        unsigned v = __builtin_nontemporal_load(bucket + e);
        int slot = atomicAdd(&cur[v >> 17], 1);   // LDS atomic
        col[slot] = (int)(v & 0x1FFFFu);
    }
}

// ---------------- gemm2: weights-stationary grid-stride MFMA GEMM ----------------
// EPI 0: fp8(acc * dinv[row] * S), unguarded rows (zero pad-row at N)

template <int K, int OUT, int EPI, bool AF32>
__global__ __launch_bounds__(256) void gemm2_k(
    const void* __restrict__ Xv, int ldx, const unsigned short* __restrict__ Wt,
    const float* __restrict__ sb, const float* __restrict__ w3b,
    const float* __restrict__ b3, void* __restrict__ Yv, int N, int NT) {
    constexpr int LDK = K + 8;
    __shared__ __align__(16) unsigned short Bs[OUT * LDK];
    __shared__ __align__(16) unsigned short As[64 * LDK];
    int t = threadIdx.x;

    // stage B once per block (visible after first in-loop barrier)
    for (int g = t; g < OUT * (K / 8); g += 256) {
        int r = g / (K / 8), q = g - r * (K / 8);
        *(uint4*)&Bs[r * LDK + q * 8] = *(const uint4*)(Wt + r * K + q * 8);
    }

    int wv = t >> 6, lane = t & 63;
    int lm = lane & 15, lq = lane >> 4;
    constexpr int CT = OUT / 16;

    for (int tile = blockIdx.x; tile < NT; tile += gridDim.x) {
        int rowBase = tile * 64;

        // stage A tile
        if constexpr (AF32) {
            const float* X = (const float*)Xv;
            for (int g = t; g < 64 * (K / 8); g += 256) {
                int r = g / (K / 8), q = g - r * (K / 8);
                int gr = rowBase + r;
                unsigned short us[8];
                if (gr < N) {
                    float4 v0 = *(const float4*)(X + (size_t)gr * ldx + q * 8);
                    float4 v1 = *(const float4*)(X + (size_t)gr * ldx + q * 8 + 4);
                    us[0] = f2b(v0.x); us[1] = f2b(v0.y); us[2] = f2b(v0.z); us[3] = f2b(v0.w);
                    us[4] = f2b(v1.x); us[5] = f2b(v1.y); us[6] = f2b(v1.z); us[7] = f2b(v1.w);
                } else {
#pragma unroll
                    for (int j = 0; j < 8; j++) us[j] = 0;
                }
                *(uint4*)&As[r * LDK + q * 8] = *(uint4*)us;
            }
        } else {
            const unsigned short* X = (const unsigned short*)Xv;
            for (int g = t; g < 64 * (K / 8); g += 256) {
                int r = g / (K / 8), q = g - r * (K / 8);
                int gr = rowBase + r;
                uint4 v = make_uint4(0, 0, 0, 0);
                if (gr < N) v = *(const uint4*)(X + (size_t)gr * ldx + q * 8);
                *(uint4*)&As[r * LDK + q * 8] = v;
            }
        }
        __syncthreads();

        f32x4 acc[CT];
#pragma unroll
        for (int c = 0; c < CT; c++) acc[c] = (f32x4){0.f, 0.f, 0.f, 0.f};

        const unsigned short* arow = &As[(wv * 16 + lm) * LDK + lq * 8];
#pragma unroll
        for (int kt = 0; kt < K / 32; kt++) {
            bf16x8 a = *(const bf16x8*)(arow + kt * 32);
#pragma unroll
            for (int c = 0; c < CT; c++) {
                bf16x8 b = *(const bf16x8*)&Bs[(c * 16 + lm) * LDK + kt * 32 + lq * 8];
                acc[c] = __builtin_amdgcn_mfma_f32_16x16x32_bf16(a, b, acc[c], 0, 0, 0);
            }
        }

        // epilogue: C/D layout col=lane&15, row=(lane>>4)*4+reg [m89/m91]
        int r0 = rowBase + wv * 16 + lq * 4;
        if constexpr (EPI == 0) {
#pragma unroll
            for (int r = 0; r < 4; r++) {
                int gr = r0 + r;
                float scale = (gr < N) ? sb[gr] * S_FP8 : 0.f;
#pragma unroll
                for (int c = 0; c < CT; c++) {
                    int colg = c * 16 + lm;
                    ((unsigned char*)Yv)[(size_t)gr * OUT + colg] = f2fp8(acc[c][r] * scale);
                }
            }
        }
        __syncthreads();   // protect As before next tile's staging
    }
}

// ---------------- aggregation (one node per wave; R9-proven) ----------------

template <bool RELU>
__global__ __launch_bounds__(256) void agg128_k(
    const unsigned char* __restrict__ H,   // [(Npad+64),128] fp8, rows>=N zero
    const int* __restrict__ rowptr, const int* __restrict__ col,
    const float* __restrict__ dinv, const float* __restrict__ bias,
    unsigned short* __restrict__ Y, int N, int Ecap) {
    int tid = threadIdx.x;
    int node = blockIdx.x * 4 + (tid >> 6);
    if (node >= N) return;
    int lane = tid & 63;
    int grp = lane >> 4;
    int li8 = (lane & 15) * 8;

    f32x2 a01 = {0.f, 0.f}, a23 = {0.f, 0.f}, a45 = {0.f, 0.f}, a67 = {0.f, 0.f};
    if (grp == 0) {
        uint2 u = *(const uint2*)(H + (size_t)node * 128 + li8);
        acc8(u, a01, a23, a45, a67);
    }

    int start = rowptr[node], end = rowptr[node + 1];
    for (int e0 = start; e0 < end; e0 += 64) {
        int cv = col[min(e0 + lane, Ecap - 1)];
        int quads = min(64, end - e0) >> 2;
        for (int q = 0; q < quads; q += 2) {
            int s0 = __shfl(cv, 4 * q + grp, 64);
            int s1 = __shfl(cv, 4 * q + 4 + grp, 64);
            uint2 u0 = *(const uint2*)(H + (size_t)s0 * 128 + li8);
            uint2 u1 = *(const uint2*)(H + (size_t)s1 * 128 + li8);
            acc8(u0, a01, a23, a45, a67);
            acc8(u1, a01, a23, a45, a67);
        }
    }

#pragma unroll
    for (int w = 16; w < 64; w <<= 1) {
        a01[0] += __shfl_xor(a01[0], w, 64); a01[1] += __shfl_xor(a01[1], w, 64);
        a23[0] += __shfl_xor(a23[0], w, 64); a23[1] += __shfl_xor(a23[1], w, 64);
        a45[0] += __shfl_xor(a45[0], w, 64); a45[1] += __shfl_xor(a45[1], w, 64);
        a67[0] += __shfl_xor(a67[0], w, 64); a67[1] += __shfl_xor(a67[1], w, 64);
    }

    if (grp == 0) {
        float dv = dinv[node] * S_FP8_INV;
        float4 b0 = *(const float4*)(bias + li8);
        float4 b1 = *(const float4*)(bias + li8 + 4);
        float o0 = a01[0] * dv + b0.x, o1 = a01[1] * dv + b0.y;
        float o2 = a23[0] * dv + b0.z, o3 = a23[1] * dv + b0.w;
        float o4 = a45[0] * dv + b1.x, o5 = a45[1] * dv + b1.y;
        float o6 = a67[0] * dv + b1.z, o7 = a67[1] * dv + b1.w;
        if (RELU) {
            o0 = fmaxf(o0, 0.f); o1 = fmaxf(o1, 0.f); o2 = fmaxf(o2, 0.f); o3 = fmaxf(o3, 0.f);
            o4 = fmaxf(o4, 0.f); o5 = fmaxf(o5, 0.f); o6 = fmaxf(o6, 0.f); o7 = fmaxf(o7, 0.f);
        }
        unsigned short us[8] = {f2b(o0), f2b(o1), f2b(o2), f2b(o3),
                                f2b(o4), f2b(o5), f2b(o6), f2b(o7)};
        *(uint4*)(Y + (size_t)node * 128 + li8) = *(uint4*)us;
    }
}

__global__ __launch_bounds__(256) void agg64_k(
    const unsigned char* __restrict__ H,   // [(Npad+64),64] fp8, rows>=N zero
    const int* __restrict__ rowptr, const int* __restrict__ col,
    const float* __restrict__ dinv, const float* __restrict__ bias,
    unsigned short* __restrict__ Y, int N, int Ecap) {
    int tid = threadIdx.x;
    int node = blockIdx.x * 4 + (tid >> 6);
    if (node >= N) return;
    int lane = tid & 63;
    int grp = lane >> 3;
    int li8 = (lane & 7) * 8;

    f32x2 a01 = {0.f, 0.f}, a23 = {0.f, 0.f}, a45 = {0.f, 0.f}, a67 = {0.f, 0.f};
    if (grp == 0) {
        uint2 u = *(const uint2*)(H + (size_t)node * 64 + li8);
        acc8(u, a01, a23, a45, a67);
    }

    int start = rowptr[node], end = rowptr[node + 1];
    for (int e0 = start; e0 < end; e0 += 64) {
        int cv = col[min(e0 + lane, Ecap - 1)];
        int octs = min(64, end - e0) >> 3;
        int o = 0;
        for (; o + 2 <= octs; o += 2) {
            int s0 = __shfl(cv, 8 * o + grp, 64);
            int s1 = __shfl(cv, 8 * o + 8 + grp, 64);
            uint2 u0 = *(const uint2*)(H + (size_t)s0 * 64 + li8);
            uint2 u1 = *(const uint2*)(H + (size_t)s1 * 64 + li8);
            acc8(u0, a01, a23, a45, a67);
            acc8(u1, a01, a23, a45, a67);
        }
        if (o < octs) {
            int s0 = __shfl(cv, 8 * o + grp, 64);
            uint2 u0 = *(const uint2*)(H + (size_t)s0 * 64 + li8);
            acc8(u0, a01, a23, a45, a67);
        }
    }

#pragma unroll
    for (int w = 8; w < 64; w <<= 1) {
        a01[0] += __shfl_xor(a01[0], w, 64); a01[1] += __shfl_xor(a01[1], w, 64);
        a23[0] += __shfl_xor(a23[0], w, 64); a23[1] += __shfl_xor(a23[1], w, 64);
        a45[0] += __shfl_xor(a45[0], w, 64); a45[1] += __shfl_xor(a45[1], w, 64);
        a67[0] += __shfl_xor(a67[0], w, 64); a67[1] += __shfl_xor(a67[1], w, 64);
    }

    if (grp == 0) {
        float dv = dinv[node] * S_FP8_INV;
        float4 b0 = *(const float4*)(bias + li8);
        float4 b1 = *(const float4*)(bias + li8 + 4);
        unsigned short us[8] = {
            f2b(a01[0] * dv + b0.x), f2b(a01[1] * dv + b0.y),
            f2b(a23[0] * dv + b0.z), f2b(a23[1] * dv + b0.w),
            f2b(a45[0] * dv + b1.x), f2b(a45[1] * dv + b1.y),
            f2b(a67[0] * dv + b1.z), f2b(a67[1] * dv + b1.w)};
        *(uint4*)(Y + (size_t)node * 64 + li8) = *(uint4*)us;
    }
}

// ---------------- actor+critic heads: one launch, block-specialized ----------------
// Blocks [0,GH): actor (L1 relu -> L2 relu -> logits -> softmax -> out[0..8))
// Blocks [GH,2GH): critic (L1 relu -> L2 relu -> value -> out[8])
// Each block runs ONE path (uniform branch) -> VGPR = max of single paths.
// Weights LDS-staged once per block; per 64-row tile each wave handles its
// own 16 rows end-to-end through wave-private LDS (no per-tile barriers).

__global__ __launch_bounds__(256) void headsB_k(
    const unsigned short* __restrict__ h3,    // [N,64] bf16
    const unsigned short* __restrict__ Wh1t,  // [256][64]: actor rows 0..127, critic 128..255
    const float* __restrict__ ba1, const float* __restrict__ bc1,
    const unsigned short* __restrict__ Wa2t,  // [64][128]
    const float* __restrict__ ba2,
    const unsigned short* __restrict__ Wc2t,  // [64][128]
    const float* __restrict__ bc2,
    const float* __restrict__ Wa3, const float* __restrict__ ba3,
    const float* __restrict__ Wc3, const float* __restrict__ bc3,
    float* __restrict__ out, int N, int NT, int GH) {
    constexpr int LD64 = 72, LD128 = 136;
    __shared__ __align__(16) unsigned short Bs1[128 * LD64];   // 18.4KB
    __shared__ __align__(16) unsigned short Bs2[64 * LD128];   // 17.4KB
    __shared__ __align__(16) unsigned short As[4 * 16 * LD64]; //  9.2KB
    __shared__ __align__(16) unsigned short A1[4 * 16 * LD128];// 17.4KB
    int t = threadIdx.x, wv = t >> 6, lane = t & 63;
    int lm = lane & 15, lq = lane >> 4;

    bool actor = (int)blockIdx.x < GH;
    const unsigned short* W1t = actor ? Wh1t : Wh1t + 128 * 64;
    const float* b1v = actor ? ba1 : bc1;
    const unsigned short* W2t = actor ? Wa2t : Wc2t;
    const float* b2v = actor ? ba2 : bc2;
    const float* w3  = actor ? Wa3 : Wc3;
    const float* b3v = actor ? ba3 : bc3;
    int tile0 = actor ? (int)blockIdx.x : (int)blockIdx.x - GH;

    // stage head weights once per block
    for (int g = t; g < 128 * 8; g += 256) {
        int r = g >> 3, q = g & 7;
        *(uint4*)&Bs1[r * LD64 + q * 8] = *(const uint4*)(W1t + r * 64 + q * 8);
    }
    for (int g = t; g < 64 * 16; g += 256) {
        int r = g >> 4, q = g & 15;
        *(uint4*)&Bs2[r * LD128 + q * 8] = *(const uint4*)(W2t + r * 128 + q * 8);
    }
    __syncthreads();

    unsigned short* Asw = &As[wv * 16 * LD64];
    unsigned short* A1w = &A1[wv * 16 * LD128];

    for (int tile = tile0; tile < NT; tile += GH) {
        int rowBase = tile * 64 + wv * 16;

        // stage wave's 16 h3 rows
        for (int g = lane; g < 16 * 8; g += 64) {
            int r = g >> 3, q = g & 7;
            int gr = rowBase + r;
            uint4 v = make_uint4(0, 0, 0, 0);
            if (gr < N) v = *(const uint4*)(h3 + (size_t)gr * 64 + q * 8);
            *(uint4*)&Asw[r * LD64 + q * 8] = v;
        }

        // L1: 16x128, K=64
        f32x4 acc1[8];
#pragma unroll
        for (int c = 0; c < 8; c++) acc1[c] = (f32x4){0.f, 0.f, 0.f, 0.f};
        const unsigned short* arow = &Asw[lm * LD64 + lq * 8];
#pragma unroll
        for (int kt = 0; kt < 2; kt++) {
            bf16x8 a = *(const bf16x8*)(arow + kt * 32);
#pragma unroll
            for (int c = 0; c < 8; c++) {
                bf16x8 b = *(const bf16x8*)&Bs1[(c * 16 + lm) * LD64 + kt * 32 + lq * 8];
                acc1[c] = __builtin_amdgcn_mfma_f32_16x16x32_bf16(a, b, acc1[c], 0, 0, 0);
            }
        }
        // relu + bf16 -> wave-private A1
#pragma unroll
        for (int r = 0; r < 4; r++) {
            int lr = lq * 4 + r;
#pragma unroll
            for (int c = 0; c < 8; c++) {
                int colg = c * 16 + lm;
                float v = fmaxf(acc1[c][r] + b1v[colg], 0.f);
                A1w[lr * LD128 + colg] = f2b(v);
            }
        }

        // L2: 16x64, K=128
        f32x4 acc[4];
#pragma unroll
        for (int c = 0; c < 4; c++) acc[c] = (f32x4){0.f, 0.f, 0.f, 0.f};
        const unsigned short* arow2 = &A1w[lm * LD128 + lq * 8];
#pragma unroll
        for (int kt = 0; kt < 4; kt++) {
            bf16x8 a = *(const bf16x8*)(arow2 + kt * 32);
#pragma unroll
            for (int c = 0; c < 4; c++) {
                bf16x8 b = *(const bf16x8*)&Bs2[(c * 16 + lm) * LD128 + kt * 32 + lq * 8];
                acc[c] = __builtin_amdgcn_mfma_f32_16x16x32_bf16(a, b, acc[c], 0, 0, 0);
            }
        }

        int r0 = rowBase + lq * 4;
        if (actor) {
            float l[4][8];
#pragma unroll
            for (int r = 0; r < 4; r++)
#pragma unroll
                for (int a = 0; a < 8; a++) l[r][a] = 0.f;
#pragma unroll
            for (int c = 0; c < 4; c++) {
                int colg = c * 16 + lm;
#pragma unroll
                for (int r = 0; r < 4; r++) {
                    float v = fmaxf(acc[c][r] + b2v[colg], 0.f);
#pragma unroll
                    for (int a = 0; a < 8; a++)
                        l[r][a] = fmaf(v, w3[colg * 8 + a], l[r][a]);
                }
            }
#pragma unroll
            for (int w = 1; w < 16; w <<= 1)
#pragma unroll
                for (int r = 0; r < 4; r++)
#pragma unroll
                    for (int a = 0; a < 8; a++)
                        l[r][a] += __shfl_xor(l[r][a], w, 64);
            if (lm < 8) {
#pragma unroll
                for (int r = 0; r < 4; r++) {
                    int gr = r0 + r;
                    if (gr < N) {
                        float lg[8], m = -1e30f;
#pragma unroll
                        for (int a = 0; a < 8; a++) { lg[a] = l[r][a] + b3v[a]; m = fmaxf(m, lg[a]); }
                        float sum = 0.f;
#pragma unroll
                        for (int a = 0; a < 8; a++) { lg[a] = expf(lg[a] - m); sum += lg[a]; }
                        out[(size_t)gr * 9 + lm] = lg[lm] / sum;
                    }
                }
            }
        } else {   // critic value
            float lv[4] = {0.f, 0.f, 0.f, 0.f};
#pragma unroll
            for (int c = 0; c < 4; c++) {
                int colg = c * 16 + lm;
#pragma unroll
                for (int r = 0; r < 4; r++) {
                    float v = fmaxf(acc[c][r] + b2v[colg], 0.f);
                    lv[r] = fmaf(v, w3[colg], lv[r]);
                }
            }
#pragma unroll
            for (int w = 1; w < 16; w <<= 1)
#pragma unroll
                for (int r = 0; r < 4; r++) lv[r] += __shfl_xor(lv[r], w, 64);
            if (lm == 0) {
#pragma unroll
                for (int r = 0; r < 4; r++) {
                    int gr = r0 + r;
                    if (gr < N) out[(size_t)gr * 9 + 8] = lv[r] + b3v[0];
                }
            }
        }
    }
}

// ---------------- launch ----------------

extern "C" void kernel_launch(void* const* d_in, const int* in_sizes, int n_in,
                              void* d_out, int out_size, void* d_ws, size_t ws_size,
                              hipStream_t stream) {
    const float* x   = (const float*)d_in[0];
    const int*   ei  = (const int*)d_in[1];
    const float* W1  = (const float*)d_in[2];  const float* b1  = (const float*)d_in[3];
    const float* W2  = (const float*)d_in[4];  const float* b2  = (const float*)d_in[5];
    const float* W3  = (const float*)d_in[6];  const float* b3  = (const float*)d_in[7];
    const float* Wa1 = (const float*)d_in[8];  const float* ba1 = (const float*)d_in[9];
    const float* Wa2 = (const float*)d_in[10]; const float* ba2 = (const float*)d_in[11];
    const float* Wa3 = (const float*)d_in[12]; const float* ba3 = (const float*)d_in[13];
    const float* Wc1 = (const float*)d_in[14]; const float* bc1 = (const float*)d_in[15];
    const float* Wc2 = (const float*)d_in[16]; const float* bc2 = (const float*)d_in[17];
    const float* Wc3 = (const float*)d_in[18]; const float* bc3 = (const float*)d_in[19];
    float* out = (float*)d_out;

    const int N = in_sizes[0] / 128;     // 100000
    const int E = in_sizes[1] / 2;       // 3200000
    const int* src = ei;
    const int* dst = ei + E;
    const int Ecap = E + 8 * N;          // padded-CSR capacity
    const int Npad = ((N + 63) / 64) * 64;
    const int NT   = (N + 63) / 64;      // 1563 row tiles

    // workspace layout
    size_t off = 0;
    auto take = [&](size_t bytes) { size_t o = off; off = WS_ALIGN(off + bytes); return o; };
    char* ws = (char*)d_ws;
    unsigned short* h3     = (unsigned short*)(ws + take((size_t)N * 64 * 2));       // 12.8MB
    unsigned short* h      = (unsigned short*)(ws + take((size_t)N * 128 * 2));      // 25.6MB
    unsigned char*  hpr8   = (unsigned char*) (ws + take((size_t)(Npad + 64) * 128));// 12.8MB
    int*            col    = (int*)(ws + take((size_t)Ecap * 4));                    // 16MB
    unsigned short* wt     = (unsigned short*)(ws + take(73728 * 2));
    float* dinv   = (float*)(ws + take((size_t)(N + 64) * 4));
    int*   cnt    = (int*)  (ws + take((size_t)N * 4));
    int*   rowptr = (int*)  (ws + take((size_t)(N + 1) * 4));
    int*   bcnt   = (int*)  (ws + take((size_t)RNG * NB * 4));
    int*   base   = (int*)  (ws + take((size_t)RNG * NB * 4));
    int*   rtot   = (int*)  (ws + take(RNG * 4));
    int*   bsum   = (int*)  (ws + take(512 * 4));
    // aliases: bucket (12.8MB) on h [h written first by agg128, after fill2];
    // hist (6.4MB) on h3 [h3 written only by agg64, after fill2].
    unsigned* bucket = (unsigned*)h;
    int* hist = (int*)h3;
    (void)ws_size; (void)n_in; (void)out_size;

    const int nb  = (N + 255) / 256;     // 391
    const int GG128 = 768;               // gemm2<128,128>: 3 blocks/CU by LDS
    const int GG64  = 1024;              // gemm2<128,64>: 4 blocks/CU by LDS
    const int GH    = 512;               // heads: blocks per head (62.4KB LDS -> 2/CU)

    const unsigned short* W1t  = wt;
    const unsigned short* W2t  = wt + 16384;
    const unsigned short* W3t  = wt + 32768;
    const unsigned short* Wh1t = wt + 40960;   // [256][64] concat actor|critic L1
    const unsigned short* Wa2t = wt + 57344;
    const unsigned short* Wc2t = wt + 65536;

    // CSR build (+ folded weight prep in bucket_count)
    bucket_count_k<<<NB, 256, 0, stream>>>(dst, bcnt, E,
                                           W1, W2, W3, Wa1, Wc1, Wa2, Wc2, wt);
    rsum_k<<<RNG, 256, 0, stream>>>(bcnt, base, rtot);
    bucket_scatter_k<<<NB, 256, 0, stream>>>(src, dst, base, rtot, bucket, E);
    hist_bucket_k<<<RNG * CHK, 256, 0, stream>>>(bucket, rtot, hist);
    sum_hist_dinv_k<<<nb, 256, 0, stream>>>(hist, cnt, dinv, bsum, N);
    scan_off_pad_k<<<nb, 256, 0, stream>>>(cnt, bsum, rowptr, hist, col, N);
    fill2_k<<<RNG * CHK, 256, 0, stream>>>(bucket, rtot, hist, col);

    // GCN layer 1..3 (gemm -> fp8 -> gather-agg)
    gemm2_k<128, 128, 0, true><<<GG128, 256, 0, stream>>>(
        x, 128, W1t, dinv, nullptr, nullptr, hpr8, N, NT);
    agg128_k<true><<<(N + 3) / 4, 256, 0, stream>>>(hpr8, rowptr, col, dinv, b1, h, N, Ecap);
    gemm2_k<128, 128, 0, false><<<GG128, 256, 0, stream>>>(
        h, 128, W2t, dinv, nullptr, nullptr, hpr8, N, NT);
    agg128_k<true><<<(N + 3) / 4, 256, 0, stream>>>(hpr8, rowptr, col, dinv, b2, h, N, Ecap);
    gemm2_k<128, 64, 0, false><<<GG64, 256, 0, stream>>>(
        h, 128, W3t, dinv, nullptr, nullptr, hpr8, N, NT);
    agg64_k<<<(N + 3) / 4, 256, 0, stream>>>(hpr8, rowptr, col, dinv, b3, h3, N, Ecap);

    // actor+critic heads, one launch (h3 -> out)
    headsB_k<<<2 * GH, 256, 0, stream>>>(
        h3, Wh1t, ba1, bc1, Wa2t, ba2, Wc2t, bc2, Wa3, ba3, Wc3, bc3, out, N, NT, GH);
}

// Round 7
// 456.495 us; speedup vs baseline: 1.1127x; 1.0135x over previous
//
#include <hip/hip_runtime.h>
#include <hip/hip_bf16.h>
#include <math.h>

// ---------------------------------------------------------------------------
// FederatedPPOAgent: 3x GCNConv (N=100k, E=3.2M, D=128) + actor/critic MLPs.
//
// R16 changes vs R15 (gemm epilogue store-pack via channel permutation):
//  - EPI0 wrote 32 scattered 1-byte stores/thread (MFMA C-layout puts a row's
//    consecutive output bytes in different lanes). Redefine H channel order:
//    position p128(n) = (n&15)*8 + n>>4 (p64 analogous). Lane lm then owns 8
//    consecutive bytes/row -> cvt_pk_fp8 pack + ONE 8B store (4 stores/thread,
//    coalesced 128B per quarter-wave).
//  - Consistency: W2t/W3t/Wa1/Wc1 K-rows stored permuted at prep; permuted
//    bias copies b1p/b2p/b3p; agg kernels take permuted biases. Arithmetic
//    identical -> absmax unchanged.
//  - agg128/agg64/heads/CSR structure unchanged (gather at HW ceiling).
// ---------------------------------------------------------------------------

#define WS_ALIGN(x) (((x) + 255) & ~(size_t)255)

constexpr int RNG  = 64;        // node ranges
constexpr int NRG  = 1563;      // nodes per range (64*1563 >= 100000)
constexpr int NB   = 1024;      // bucket-phase blocks
constexpr int CHK  = 16;        // per-range fill chunks

constexpr float S_FP8     = 64.0f;
constexpr float S_FP8_INV = 1.0f / 64.0f;

using bf16x8 = __attribute__((ext_vector_type(8))) short;
using f32x4  = __attribute__((ext_vector_type(4))) float;
using f32x2  = __attribute__((ext_vector_type(2))) float;

__device__ __forceinline__ float b2f(unsigned short u) {
    return __uint_as_float(((unsigned int)u) << 16);
}
__device__ __forceinline__ unsigned short f2b(float f) {
    __hip_bfloat16 hb = __float2bfloat16(f);
    return *(unsigned short*)&hb;
}
__device__ __forceinline__ unsigned char f2fp8(float f) {
    return (unsigned char)(__builtin_amdgcn_cvt_pk_fp8_f32(f, f, 0, false) & 0xff);
}
__device__ __forceinline__ int pad8(int v) { return (v + 7) & ~7; }

// 8 fp8 (uint2) -> 4 packed-f32 accumulators
__device__ __forceinline__ void acc8(uint2 u, f32x2& a01, f32x2& a23,
                                     f32x2& a45, f32x2& a67) {
    a01 += __builtin_amdgcn_cvt_pk_f32_fp8((int)u.x, false);
    a23 += __builtin_amdgcn_cvt_pk_f32_fp8((int)u.x, true);
    a45 += __builtin_amdgcn_cvt_pk_f32_fp8((int)u.y, false);
    a67 += __builtin_amdgcn_cvt_pk_f32_fp8((int)u.y, true);
}

// ---------------- CSR build ----------------

// + folded weight prep: fp32 W[K][OUT] -> bf16 W^T[OUT][K], with K-dim
// channel permutation where the producing layer writes packed output:
//   p128(k) = (k&15)*8 + (k>>4)   [gemm OUT=128 producers: W2,W3 K-rows]
//   p64(k)  = (k&15)*4 + (k>>4)   [gemm OUT=64 producer  : Wa1,Wc1 K-rows]
// + permuted bias copies bp[0..127]=b1, [128..255]=b2, [256..319]=b3.
__global__ __launch_bounds__(256) void bucket_count_k(
    const int* __restrict__ dst, int* __restrict__ bcnt, int E,
    const float* __restrict__ W1, const float* __restrict__ W2,
    const float* __restrict__ W3, const float* __restrict__ Wa1,
    const float* __restrict__ Wc1, const float* __restrict__ Wa2,
    const float* __restrict__ Wc2,
    const float* __restrict__ b1, const float* __restrict__ b2,
    const float* __restrict__ b3,
    unsigned short* __restrict__ wt, float* __restrict__ bp) {
    __shared__ int c64[RNG];
    int b = blockIdx.x, t = threadIdx.x;

    // folded prep (74048 elems; grid has 262144 threads)
    int gi = b * 256 + t;
    if (gi < 73728) {
        const float* W; int off, K, OUT; int pm = 0;   // 0:none 1:p128 2:p64
        if (gi < 16384)      { W = W1;  off = 0;     K = 128; OUT = 128; }
        else if (gi < 32768) { W = W2;  off = 16384; K = 128; OUT = 128; pm = 1; }
        else if (gi < 40960) { W = W3;  off = 32768; K = 128; OUT = 64;  pm = 1; }
        else if (gi < 49152) { W = Wa1; off = 40960; K = 64;  OUT = 128; pm = 2; }
        else if (gi < 57344) { W = Wc1; off = 49152; K = 64;  OUT = 128; pm = 2; }
        else if (gi < 65536) { W = Wa2; off = 57344; K = 128; OUT = 64; }
        else                 { W = Wc2; off = 65536; K = 128; OUT = 64; }
        int j = gi - off, k = j / OUT, n = j - k * OUT;
        int kp = (pm == 1) ? ((k & 15) * 8 + (k >> 4))
               : (pm == 2) ? ((k & 15) * 4 + (k >> 4)) : k;
        wt[off + n * K + kp] = f2b(W[j]);
    } else if (gi < 74048) {
        int j = gi - 73728;
        if (j < 128)      bp[(j & 15) * 8 + (j >> 4)] = b1[j];
        else if (j < 256) { int j2 = j - 128; bp[128 + (j2 & 15) * 8 + (j2 >> 4)] = b2[j2]; }
        else              { int j3 = j - 256; bp[256 + (j3 & 15) * 4 + (j3 >> 4)] = b3[j3]; }
    }

    if (t < RNG) c64[t] = 0;
    __syncthreads();
    int ec = (E + NB - 1) / NB;
    int e0 = b * ec, e1 = min(E, e0 + ec);
    for (int e = e0 + t; e < e1; e += 256) {
        int d = __builtin_nontemporal_load(dst + e);
        atomicAdd(&c64[d / NRG], 1);
    }
    __syncthreads();
    if (t < RNG) bcnt[t * NB + b] = c64[t];
}

// block r: exclusive scan of bcnt[r][0..NB) -> base, total -> rtot[r]
__global__ __launch_bounds__(256) void rsum_k(
    const int* __restrict__ bcnt, int* __restrict__ base, int* __restrict__ rtot) {
    __shared__ int s[256];
    int r = blockIdx.x, t = threadIdx.x;
    const int* row = bcnt + (size_t)r * NB;
    int v[4], loc = 0;
#pragma unroll
    for (int j = 0; j < 4; j++) { v[j] = row[t * 4 + j]; loc += v[j]; }
    s[t] = loc;
    __syncthreads();
    for (int d = 1; d < 256; d <<= 1) {
        int x = (t >= d) ? s[t - d] : 0;
        __syncthreads();
        s[t] += x;
        __syncthreads();
    }
    int run = s[t] - loc;   // exclusive
    int* bp2 = base + (size_t)r * NB + t * 4;
#pragma unroll
    for (int j = 0; j < 4; j++) { bp2[j] = run; run += v[j]; }
    if (t == 255) rtot[r] = s[255];
}

__global__ __launch_bounds__(256) void bucket_scatter_k(
    const int* __restrict__ src, const int* __restrict__ dst,
    const int* __restrict__ base, const int* __restrict__ rtot,
    unsigned* __restrict__ bucket, int E) {
    __shared__ int cur[RNG];
    __shared__ int rt[RNG];
    int b = blockIdx.x, t = threadIdx.x;
    if (t < RNG) rt[t] = rtot[t];
    __syncthreads();
    if (t < RNG) {
        int run = 0;
        for (int j = 0; j < t; j++) run += rt[j];   // bstart[t] inline
        cur[t] = run + base[(size_t)t * NB + b];
    }
    __syncthreads();
    int ec = (E + NB - 1) / NB;
    int e0 = b * ec, e1 = min(E, e0 + ec);
    for (int e = e0 + t; e < e1; e += 256) {
        int d = __builtin_nontemporal_load(dst + e);
        int sv = __builtin_nontemporal_load(src + e);
        int r = d / NRG;
        int pos = atomicAdd(&cur[r], 1);
        bucket[pos] = ((unsigned)(d - r * NRG) << 17) | (unsigned)sv;
    }
}

__global__ __launch_bounds__(256) void hist_bucket_k(
    const unsigned* __restrict__ bucket, const int* __restrict__ rtot,
    int* __restrict__ hist) {
    __shared__ int h[NRG];
    __shared__ int ss[2];
    int b = blockIdx.x, r = b & 63, c2 = b >> 6, t = threadIdx.x;
    for (int i = t; i < NRG; i += 256) h[i] = 0;
    if (t == 0) {
        int run = 0;
        for (int j = 0; j < r; j++) run += rtot[j];
        ss[0] = run; ss[1] = run + rtot[r];
    }
    __syncthreads();
    int s0 = ss[0], s1 = ss[1];
    int ec = (s1 - s0 + CHK - 1) / CHK;
    int e0 = s0 + c2 * ec, e1 = min(s1, e0 + ec);
    for (int e = e0 + t; e < e1; e += 256) {
        unsigned v = __builtin_nontemporal_load(bucket + e);
        atomicAdd(&h[v >> 17], 1);
    }
    __syncthreads();
    int* out = hist + ((size_t)r * CHK + c2) * NRG;
    for (int i = t; i < NRG; i += 256) out[i] = h[i];
}

// per-node degree + dinv + per-block padded-count sum (chunk_sum folded in)
__global__ __launch_bounds__(256) void sum_hist_dinv_k(
    const int* __restrict__ hist, int* __restrict__ cnt,
    float* __restrict__ dinv, int* __restrict__ bsum, int N) {
    __shared__ int sd[256];
    int t = threadIdx.x;
    int i = blockIdx.x * 256 + t;
    int s = 0;
    if (i < N) {
        int r = i / NRG, li = i - r * NRG;
        const int* hp = hist + ((size_t)r * CHK) * NRG + li;
#pragma unroll
        for (int c = 0; c < CHK; c++) s += hp[(size_t)c * NRG];
        cnt[i] = s;
        dinv[i] = rsqrtf((float)s + 1.0f);   // +1: self loop
    }
    sd[t] = (i < N) ? pad8(s) : 0;
    __syncthreads();
    for (int d = 128; d > 0; d >>= 1) {
        if (t < d) sd[t] += sd[t + d];
        __syncthreads();
    }
    if (t == 0) bsum[blockIdx.x] = sd[0];
}

// scan_final + boff-from-bsum (scan_mid folded) + offsets + pad_col
__global__ void scan_off_pad_k(const int* __restrict__ cnt, const int* __restrict__ bsum,
                               int* __restrict__ rowptr, int* __restrict__ hist,
                               int* __restrict__ col, int N) {
    __shared__ int s[256];
    int t = threadIdx.x, b = blockIdx.x;

    // boff = sum of bsum[j] for j < b (bsum is L2-hot, <=391 ints)
    int part = 0;
    for (int j = t; j < b; j += 256) part += bsum[j];
    s[t] = part;
    __syncthreads();
    for (int d = 128; d > 0; d >>= 1) {
        if (t < d) s[t] += s[t + d];
        __syncthreads();
    }
    int boffv = s[0];
    __syncthreads();

    int i = b * 256 + t;
    int cv = (i < N) ? cnt[i] : 0;
    int v = pad8(cv);
    if (i >= N) v = 0;
    s[t] = v;
    __syncthreads();
    for (int d = 1; d < 256; d <<= 1) {
        int x = (t >= d) ? s[t - d] : 0;
        __syncthreads();
        s[t] += x;
        __syncthreads();
    }
    if (b == (int)gridDim.x - 1 && t == 255) rowptr[N] = boffv + s[255];
    if (i < N) {
        int rp = s[t] - v + boffv;
        rowptr[i] = rp;
        // offsets: hist[r][c][li] -> running cursor
        int r = i / NRG, li = i - r * NRG;
        int* hp = hist + ((size_t)r * CHK) * NRG + li;
        int run = rp;
#pragma unroll
        for (int c = 0; c < CHK; c++) {
            int hv = hp[(size_t)c * NRG];
            hp[(size_t)c * NRG] = run;
            run += hv;
        }
        // pad slots -> zero-row N
        for (int e = rp + cv; e < rp + v; e++) col[e] = N;
    }
}

__global__ __launch_bounds__(256) void fill2_k(
    const unsigned* __restrict__ bucket, const int* __restrict__ rtot,
    const int* __restrict__ hist, int* __restrict__ col) {
    __shared__ int cur[NRG];
    __shared__ int ss[2];
    int b = blockIdx.x, r = b & 63, c2 = b >> 6, t = threadIdx.x;
    const int* hp = hist + ((size_t)r * CHK + c2) * NRG;
    for (int i = t; i < NRG; i += 256) cur[i] = hp[i];
    if (t == 0) {
        int run = 0;
        for (int j = 0; j < r; j++) run += rtot[j];
        ss[0] = run; ss[1] = run + rtot[r];
    }
    __syncthreads();
    int s0 = ss[0], s1 = ss[1];
    int ec = (s1 - s0 + CHK - 1) / CHK;
    int e0 = s0 + c2 * ec, e1 = min(s1, e0 + ec);
    for (int e = e0 + t; e < e1; e += 256) {
        unsigned v = __builtin_nontemporal_load(bucket + e);
        int slot = atomicAdd(&cur[v >> 17], 1);   // LDS atomic
        col[slot] = (int)(v & 0x1FFFFu);
    }
}

// ---------------- gemm2: weights-stationary grid-stride MFMA GEMM ----------------
// EPI 0: packed fp8(acc * dinv[row] * S) in PERMUTED channel order:
//   position p = lm*(CT) + c  (lane lm owns CT consecutive bytes per row).
// Consumers (agg bias, next-layer W K-rows) are permuted to match at prep.

template <int K, int OUT, int EPI, bool AF32>
__global__ __launch_bounds__(256) void gemm2_k(
    const void* __restrict__ Xv, int ldx, const unsigned short* __restrict__ Wt,
    const float* __restrict__ sb, const float* __restrict__ w3b,
    const float* __restrict__ b3, void* __restrict__ Yv, int N, int NT) {
    constexpr int LDK = K + 8;
    __shared__ __align__(16) unsigned short Bs[OUT * LDK];
    __shared__ __align__(16) unsigned short As[64 * LDK];
    int t = threadIdx.x;

    // stage B once per block (visible after first in-loop barrier)
    for (int g = t; g < OUT * (K / 8); g += 256) {
        int r = g / (K / 8), q = g - r * (K / 8);
        *(uint4*)&Bs[r * LDK + q * 8] = *(const uint4*)(Wt + r * K + q * 8);
    }

    int wv = t >> 6, lane = t & 63;
    int lm = lane & 15, lq = lane >> 4;
    constexpr int CT = OUT / 16;

    for (int tile = blockIdx.x; tile < NT; tile += gridDim.x) {
        int rowBase = tile * 64;

        // stage A tile
        if constexpr (AF32) {
            const float* X = (const float*)Xv;
            for (int g = t; g < 64 * (K / 8); g += 256) {
                int r = g / (K / 8), q = g - r * (K / 8);
                int gr = rowBase + r;
                unsigned short us[8];
                if (gr < N) {
                    float4 v0 = *(const float4*)(X + (size_t)gr * ldx + q * 8);
                    float4 v1 = *(const float4*)(X + (size_t)gr * ldx + q * 8 + 4);
                    us[0] = f2b(v0.x); us[1] = f2b(v0.y); us[2] = f2b(v0.z); us[3] = f2b(v0.w);
                    us[4] = f2b(v1.x); us[5] = f2b(v1.y); us[6] = f2b(v1.z); us[7] = f2b(v1.w);
                } else {
#pragma unroll
                    for (int j = 0; j < 8; j++) us[j] = 0;
                }
                *(uint4*)&As[r * LDK + q * 8] = *(uint4*)us;
            }
        } else {
            const unsigned short* X = (const unsigned short*)Xv;
            for (int g = t; g < 64 * (K / 8); g += 256) {
                int r = g / (K / 8), q = g - r * (K / 8);
                int gr = rowBase + r;
                uint4 v = make_uint4(0, 0, 0, 0);
                if (gr < N) v = *(const uint4*)(X + (size_t)gr * ldx + q * 8);
                *(uint4*)&As[r * LDK + q * 8] = v;
            }
        }
        __syncthreads();

        f32x4 acc[CT];
#pragma unroll
        for (int c = 0; c < CT; c++) acc[c] = (f32x4){0.f, 0.f, 0.f, 0.f};

        const unsigned short* arow = &As[(wv * 16 + lm) * LDK + lq * 8];
#pragma unroll
        for (int kt = 0; kt < K / 32; kt++) {
            bf16x8 a = *(const bf16x8*)(arow + kt * 32);
#pragma unroll
            for (int c = 0; c < CT; c++) {
                bf16x8 b = *(const bf16x8*)&Bs[(c * 16 + lm) * LDK + kt * 32 + lq * 8];
                acc[c] = __builtin_amdgcn_mfma_f32_16x16x32_bf16(a, b, acc[c], 0, 0, 0);
            }
        }

        // epilogue: C/D layout col=lane&15, row=(lane>>4)*4+reg [m89/m91]
        int r0 = rowBase + wv * 16 + lq * 4;
        if constexpr (EPI == 0) {
#pragma unroll
            for (int r = 0; r < 4; r++) {
                int gr = r0 + r;
                float scale = (gr < N) ? sb[gr] * S_FP8 : 0.f;
                if constexpr (OUT == 128) {
                    unsigned w0 = 0, w1 = 0;
                    w0 = __builtin_amdgcn_cvt_pk_fp8_f32(acc[0][r] * scale, acc[1][r] * scale, w0, false);
                    w0 = __builtin_amdgcn_cvt_pk_fp8_f32(acc[2][r] * scale, acc[3][r] * scale, w0, true);
                    w1 = __builtin_amdgcn_cvt_pk_fp8_f32(acc[4][r] * scale, acc[5][r] * scale, w1, false);
                    w1 = __builtin_amdgcn_cvt_pk_fp8_f32(acc[6][r] * scale, acc[7][r] * scale, w1, true);
                    *(uint2*)((unsigned char*)Yv + (size_t)gr * 128 + lm * 8) = make_uint2(w0, w1);
                } else {   // OUT == 64
                    unsigned w0 = 0;
                    w0 = __builtin_amdgcn_cvt_pk_fp8_f32(acc[0][r] * scale, acc[1][r] * scale, w0, false);
                    w0 = __builtin_amdgcn_cvt_pk_fp8_f32(acc[2][r] * scale, acc[3][r] * scale, w0, true);
                    *(unsigned*)((unsigned char*)Yv + (size_t)gr * 64 + lm * 4) = w0;
                }
            }
        }
        __syncthreads();   // protect As before next tile's staging
    }
}

// ---------------- aggregation (one node per wave; R9-proven) ----------------
// NOTE: bias arrays are the PERMUTED copies (channel order matches packed H).

template <bool RELU>
__global__ __launch_bounds__(256) void agg128_k(
    const unsigned char* __restrict__ H,   // [(Npad+64),128] fp8, rows>=N zero
    const int* __restrict__ rowptr, const int* __restrict__ col,
    const float* __restrict__ dinv, const float* __restrict__ bias,
    unsigned short* __restrict__ Y, int N, int Ecap) {
    int tid = threadIdx.x;
    int node = blockIdx.x * 4 + (tid >> 6);
    if (node >= N) return;
    int lane = tid & 63;
    int grp = lane >> 4;
    int li8 = (lane & 15) * 8;

    f32x2 a01 = {0.f, 0.f}, a23 = {0.f, 0.f}, a45 = {0.f, 0.f}, a67 = {0.f, 0.f};
    if (grp == 0) {
        uint2 u = *(const uint2*)(H + (size_t)node * 128 + li8);
        acc8(u, a01, a23, a45, a67);
    }

    int start = rowptr[node], end = rowptr[node + 1];
    for (int e0 = start; e0 < end; e0 += 64) {
        int cv = col[min(e0 + lane, Ecap - 1)];
        int quads = min(64, end - e0) >> 2;
        for (int q = 0; q < quads; q += 2) {
            int s0 = __shfl(cv, 4 * q + grp, 64);
            int s1 = __shfl(cv, 4 * q + 4 + grp, 64);
            uint2 u0 = *(const uint2*)(H + (size_t)s0 * 128 + li8);
            uint2 u1 = *(const uint2*)(H + (size_t)s1 * 128 + li8);
            acc8(u0, a01, a23, a45, a67);
            acc8(u1, a01, a23, a45, a67);
        }
    }

#pragma unroll
    for (int w = 16; w < 64; w <<= 1) {
        a01[0] += __shfl_xor(a01[0], w, 64); a01[1] += __shfl_xor(a01[1], w, 64);
        a23[0] += __shfl_xor(a23[0], w, 64); a23[1] += __shfl_xor(a23[1], w, 64);
        a45[0] += __shfl_xor(a45[0], w, 64); a45[1] += __shfl_xor(a45[1], w, 64);
        a67[0] += __shfl_xor(a67[0], w, 64); a67[1] += __shfl_xor(a67[1], w, 64);
    }

    if (grp == 0) {
        float dv = dinv[node] * S_FP8_INV;
        float4 b0 = *(const float4*)(bias + li8);
        float4 b1 = *(const float4*)(bias + li8 + 4);
        float o0 = a01[0] * dv + b0.x, o1 = a01[1] * dv + b0.y;
        float o2 = a23[0] * dv + b0.z, o3 = a23[1] * dv + b0.w;
        float o4 = a45[0] * dv + b1.x, o5 = a45[1] * dv + b1.y;
        float o6 = a67[0] * dv + b1.z, o7 = a67[1] * dv + b1.w;
        if (RELU) {
            o0 = fmaxf(o0, 0.f); o1 = fmaxf(o1, 0.f); o2 = fmaxf(o2, 0.f); o3 = fmaxf(o3, 0.f);
            o4 = fmaxf(o4, 0.f); o5 = fmaxf(o5, 0.f); o6 = fmaxf(o6, 0.f); o7 = fmaxf(o7, 0.f);
        }
        unsigned short us[8] = {f2b(o0), f2b(o1), f2b(o2), f2b(o3),
                                f2b(o4), f2b(o5), f2b(o6), f2b(o7)};
        *(uint4*)(Y + (size_t)node * 128 + li8) = *(uint4*)us;
    }
}

__global__ __launch_bounds__(256) void agg64_k(
    const unsigned char* __restrict__ H,   // [(Npad+64),64] fp8, rows>=N zero
    const int* __restrict__ rowptr, const int* __restrict__ col,
    const float* __restrict__ dinv, const float* __restrict__ bias,
    unsigned short* __restrict__ Y, int N, int Ecap) {
    int tid = threadIdx.x;
    int node = blockIdx.x * 4 + (tid >> 6);
    if (node >= N) return;
    int lane = tid & 63;
    int grp = lane >> 3;
    int li8 = (lane & 7) * 8;

    f32x2 a01 = {0.f, 0.f}, a23 = {0.f, 0.f}, a45 = {0.f, 0.f}, a67 = {0.f, 0.f};
    if (grp == 0) {
        uint2 u = *(const uint2*)(H + (size_t)node * 64 + li8);
        acc8(u, a01, a23, a45, a67);
    }

    int start = rowptr[node], end = rowptr[node + 1];
    for (int e0 = start; e0 < end; e0 += 64) {
        int cv = col[min(e0 + lane, Ecap - 1)];
        int octs = min(64, end - e0) >> 3;
        int o = 0;
        for (; o + 2 <= octs; o += 2) {
            int s0 = __shfl(cv, 8 * o + grp, 64);
            int s1 = __shfl(cv, 8 * o + 8 + grp, 64);
            uint2 u0 = *(const uint2*)(H + (size_t)s0 * 64 + li8);
            uint2 u1 = *(const uint2*)(H + (size_t)s1 * 64 + li8);
            acc8(u0, a01, a23, a45, a67);
            acc8(u1, a01, a23, a45, a67);
        }
        if (o < octs) {
            int s0 = __shfl(cv, 8 * o + grp, 64);
            uint2 u0 = *(const uint2*)(H + (size_t)s0 * 64 + li8);
            acc8(u0, a01, a23, a45, a67);
        }
    }

#pragma unroll
    for (int w = 8; w < 64; w <<= 1) {
        a01[0] += __shfl_xor(a01[0], w, 64); a01[1] += __shfl_xor(a01[1], w, 64);
        a23[0] += __shfl_xor(a23[0], w, 64); a23[1] += __shfl_xor(a23[1], w, 64);
        a45[0] += __shfl_xor(a45[0], w, 64); a45[1] += __shfl_xor(a45[1], w, 64);
        a67[0] += __shfl_xor(a67[0], w, 64); a67[1] += __shfl_xor(a67[1], w, 64);
    }

    if (grp == 0) {
        float dv = dinv[node] * S_FP8_INV;
        float4 b0 = *(const float4*)(bias + li8);
        float4 b1 = *(const float4*)(bias + li8 + 4);
        unsigned short us[8] = {
            f2b(a01[0] * dv + b0.x), f2b(a01[1] * dv + b0.y),
            f2b(a23[0] * dv + b0.z), f2b(a23[1] * dv + b0.w),
            f2b(a45[0] * dv + b1.x), f2b(a45[1] * dv + b1.y),
            f2b(a67[0] * dv + b1.z), f2b(a67[1] * dv + b1.w)};
        *(uint4*)(Y + (size_t)node * 64 + li8) = *(uint4*)us;
    }
}

// ---------------- actor+critic heads: one launch, block-specialized ----------------
// Blocks [0,GH): actor; [GH,2GH): critic. h3 channels are p64-permuted; the
// Wh1t K-rows are stored permuted to match (prep), so the kernel is unchanged.

__global__ __launch_bounds__(256) void headsB_k(
    const unsigned short* __restrict__ h3,    // [N,64] bf16 (p64 channel order)
    const unsigned short* __restrict__ Wh1t,  // [256][64]: actor rows 0..127, critic 128..255
    const float* __restrict__ ba1, const float* __restrict__ bc1,
    const unsigned short* __restrict__ Wa2t,  // [64][128]
    const float* __restrict__ ba2,
    const unsigned short* __restrict__ Wc2t,  // [64][128]
    const float* __restrict__ bc2,
    const float* __restrict__ Wa3, const float* __restrict__ ba3,
    const float* __restrict__ Wc3, const float* __restrict__ bc3,
    float* __restrict__ out, int N, int NT, int GH) {
    constexpr int LD64 = 72, LD128 = 136;
    __shared__ __align__(16) unsigned short Bs1[128 * LD64];   // 18.4KB
    __shared__ __align__(16) unsigned short Bs2[64 * LD128];   // 17.4KB
    __shared__ __align__(16) unsigned short As[4 * 16 * LD64]; //  9.2KB
    __shared__ __align__(16) unsigned short A1[4 * 16 * LD128];// 17.4KB
    int t = threadIdx.x, wv = t >> 6, lane = t & 63;
    int lm = lane & 15, lq = lane >> 4;

    bool actor = (int)blockIdx.x < GH;
    const unsigned short* W1t = actor ? Wh1t : Wh1t + 128 * 64;
    const float* b1v = actor ? ba1 : bc1;
    const unsigned short* W2t = actor ? Wa2t : Wc2t;
    const float* b2v = actor ? ba2 : bc2;
    const float* w3  = actor ? Wa3 : Wc3;
    const float* b3v = actor ? ba3 : bc3;
    int tile0 = actor ? (int)blockIdx.x : (int)blockIdx.x - GH;

    // stage head weights once per block
    for (int g = t; g < 128 * 8; g += 256) {
        int r = g >> 3, q = g & 7;
        *(uint4*)&Bs1[r * LD64 + q * 8] = *(const uint4*)(W1t + r * 64 + q * 8);
    }
    for (int g = t; g < 64 * 16; g += 256) {
        int r = g >> 4, q = g & 15;
        *(uint4*)&Bs2[r * LD128 + q * 8] = *(const uint4*)(W2t + r * 128 + q * 8);
    }
    __syncthreads();

    unsigned short* Asw = &As[wv * 16 * LD64];
    unsigned short* A1w = &A1[wv * 16 * LD128];

    for (int tile = tile0; tile < NT; tile += GH) {
        int rowBase = tile * 64 + wv * 16;

        // stage wave's 16 h3 rows
        for (int g = lane; g < 16 * 8; g += 64) {
            int r = g >> 3, q = g & 7;
            int gr = rowBase + r;
            uint4 v = make_uint4(0, 0, 0, 0);
            if (gr < N) v = *(const uint4*)(h3 + (size_t)gr * 64 + q * 8);
            *(uint4*)&Asw[r * LD64 + q * 8] = v;
        }

        // L1: 16x128, K=64
        f32x4 acc1[8];
#pragma unroll
        for (int c = 0; c < 8; c++) acc1[c] = (f32x4){0.f, 0.f, 0.f, 0.f};
        const unsigned short* arow = &Asw[lm * LD64 + lq * 8];
#pragma unroll
        for (int kt = 0; kt < 2; kt++) {
            bf16x8 a = *(const bf16x8*)(arow + kt * 32);
#pragma unroll
            for (int c = 0; c < 8; c++) {
                bf16x8 b = *(const bf16x8*)&Bs1[(c * 16 + lm) * LD64 + kt * 32 + lq * 8];
                acc1[c] = __builtin_amdgcn_mfma_f32_16x16x32_bf16(a, b, acc1[c], 0, 0, 0);
            }
        }
        // relu + bf16 -> wave-private A1
#pragma unroll
        for (int r = 0; r < 4; r++) {
            int lr = lq * 4 + r;
#pragma unroll
            for (int c = 0; c < 8; c++) {
                int colg = c * 16 + lm;
                float v = fmaxf(acc1[c][r] + b1v[colg], 0.f);
                A1w[lr * LD128 + colg] = f2b(v);
            }
        }

        // L2: 16x64, K=128
        f32x4 acc[4];
#pragma unroll
        for (int c = 0; c < 4; c++) acc[c] = (f32x4){0.f, 0.f, 0.f, 0.f};
        const unsigned short* arow2 = &A1w[lm * LD128 + lq * 8];
#pragma unroll
        for (int kt = 0; kt < 4; kt++) {
            bf16x8 a = *(const bf16x8*)(arow2 + kt * 32);
#pragma unroll
            for (int c = 0; c < 4; c++) {
                bf16x8 b = *(const bf16x8*)&Bs2[(c * 16 + lm) * LD128 + kt * 32 + lq * 8];
                acc[c] = __builtin_amdgcn_mfma_f32_16x16x32_bf16(a, b, acc[c], 0, 0, 0);
            }
        }

        int r0 = rowBase + lq * 4;
        if (actor) {
            float l[4][8];
#pragma unroll
            for (int r = 0; r < 4; r++)
#pragma unroll
                for (int a = 0; a < 8; a++) l[r][a] = 0.f;
#pragma unroll
            for (int c = 0; c < 4; c++) {
                int colg = c * 16 + lm;
#pragma unroll
                for (int r = 0; r < 4; r++) {
                    float v = fmaxf(acc[c][r] + b2v[colg], 0.f);
#pragma unroll
                    for (int a = 0; a < 8; a++)
                        l[r][a] = fmaf(v, w3[colg * 8 + a], l[r][a]);
                }
            }
#pragma unroll
            for (int w = 1; w < 16; w <<= 1)
#pragma unroll
                for (int r = 0; r < 4; r++)
#pragma unroll
                    for (int a = 0; a < 8; a++)
                        l[r][a] += __shfl_xor(l[r][a], w, 64);
            if (lm < 8) {
#pragma unroll
                for (int r = 0; r < 4; r++) {
                    int gr = r0 + r;
                    if (gr < N) {
                        float lg[8], m = -1e30f;
#pragma unroll
                        for (int a = 0; a < 8; a++) { lg[a] = l[r][a] + b3v[a]; m = fmaxf(m, lg[a]); }
                        float sum = 0.f;
#pragma unroll
                        for (int a = 0; a < 8; a++) { lg[a] = expf(lg[a] - m); sum += lg[a]; }
                        out[(size_t)gr * 9 + lm] = lg[lm] / sum;
                    }
                }
            }
        } else {   // critic value
            float lv[4] = {0.f, 0.f, 0.f, 0.f};
#pragma unroll
            for (int c = 0; c < 4; c++) {
                int colg = c * 16 + lm;
#pragma unroll
                for (int r = 0; r < 4; r++) {
                    float v = fmaxf(acc[c][r] + b2v[colg], 0.f);
                    lv[r] = fmaf(v, w3[colg], lv[r]);
                }
            }
#pragma unroll
            for (int w = 1; w < 16; w <<= 1)
#pragma unroll
                for (int r = 0; r < 4; r++) lv[r] += __shfl_xor(lv[r], w, 64);
            if (lm == 0) {
#pragma unroll
                for (int r = 0; r < 4; r++) {
                    int gr = r0 + r;
                    if (gr < N) out[(size_t)gr * 9 + 8] = lv[r] + b3v[0];
                }
            }
        }
    }
}

// ---------------- launch ----------------

extern "C" void kernel_launch(void* const* d_in, const int* in_sizes, int n_in,
                              void* d_out, int out_size, void* d_ws, size_t ws_size,
                              hipStream_t stream) {
    const float* x   = (const float*)d_in[0];
    const int*   ei  = (const int*)d_in[1];
    const float* W1  = (const float*)d_in[2];  const float* b1  = (const float*)d_in[3];
    const float* W2  = (const float*)d_in[4];  const float* b2  = (const float*)d_in[5];
    const float* W3  = (const float*)d_in[6];  const float* b3  = (const float*)d_in[7];
    const float* Wa1 = (const float*)d_in[8];  const float* ba1 = (const float*)d_in[9];
    const float* Wa2 = (const float*)d_in[10]; const float* ba2 = (const float*)d_in[11];
    const float* Wa3 = (const float*)d_in[12]; const float* ba3 = (const float*)d_in[13];
    const float* Wc1 = (const float*)d_in[14]; const float* bc1 = (const float*)d_in[15];
    const float* Wc2 = (const float*)d_in[16]; const float* bc2 = (const float*)d_in[17];
    const float* Wc3 = (const float*)d_in[18]; const float* bc3 = (const float*)d_in[19];
    float* out = (float*)d_out;

    const int N = in_sizes[0] / 128;     // 100000
    const int E = in_sizes[1] / 2;       // 3200000
    const int* src = ei;
    const int* dst = ei + E;
    const int Ecap = E + 8 * N;          // padded-CSR capacity
    const int Npad = ((N + 63) / 64) * 64;
    const int NT   = (N + 63) / 64;      // 1563 row tiles

    // workspace layout
    size_t off = 0;
    auto take = [&](size_t bytes) { size_t o = off; off = WS_ALIGN(off + bytes); return o; };
    char* ws = (char*)d_ws;
    unsigned short* h3     = (unsigned short*)(ws + take((size_t)N * 64 * 2));       // 12.8MB
    unsigned short* h      = (unsigned short*)(ws + take((size_t)N * 128 * 2));      // 25.6MB
    unsigned char*  hpr8   = (unsigned char*) (ws + take((size_t)(Npad + 64) * 128));// 12.8MB
    int*            col    = (int*)(ws + take((size_t)Ecap * 4));                    // 16MB
    unsigned short* wt     = (unsigned short*)(ws + take(73728 * 2));
    float* bperm  = (float*)(ws + take(320 * 4));    // permuted b1(128) b2(128) b3(64)
    float* dinv   = (float*)(ws + take((size_t)(N + 64) * 4));
    int*   cnt    = (int*)  (ws + take((size_t)N * 4));
    int*   rowptr = (int*)  (ws + take((size_t)(N + 1) * 4));
    int*   bcnt   = (int*)  (ws + take((size_t)RNG * NB * 4));
    int*   base   = (int*)  (ws + take((size_t)RNG * NB * 4));
    int*   rtot   = (int*)  (ws + take(RNG * 4));
    int*   bsum   = (int*)  (ws + take(512 * 4));
    // aliases: bucket (12.8MB) on h [h written first by agg128, after fill2];
    // hist (6.4MB) on h3 [h3 written only by agg64, after fill2].
    unsigned* bucket = (unsigned*)h;
    int* hist = (int*)h3;
    (void)ws_size; (void)n_in; (void)out_size;

    const int nb  = (N + 255) / 256;     // 391
    const int GG128 = 768;               // gemm2<128,128>: 3 blocks/CU by LDS
    const int GG64  = 1024;              // gemm2<128,64>: 4 blocks/CU by LDS
    const int GH    = 512;               // heads: blocks per head (62.4KB LDS -> 2/CU)

    const unsigned short* W1t  = wt;
    const unsigned short* W2t  = wt + 16384;
    const unsigned short* W3t  = wt + 32768;
    const unsigned short* Wh1t = wt + 40960;   // [256][64] concat actor|critic L1
    const unsigned short* Wa2t = wt + 57344;
    const unsigned short* Wc2t = wt + 65536;
    const float* b1p = bperm;
    const float* b2p = bperm + 128;
    const float* b3p = bperm + 256;

    // CSR build (+ folded weight/bias prep in bucket_count)
    bucket_count_k<<<NB, 256, 0, stream>>>(dst, bcnt, E,
                                           W1, W2, W3, Wa1, Wc1, Wa2, Wc2,
                                           b1, b2, b3, wt, bperm);
    rsum_k<<<RNG, 256, 0, stream>>>(bcnt, base, rtot);
    bucket_scatter_k<<<NB, 256, 0, stream>>>(src, dst, base, rtot, bucket, E);
    hist_bucket_k<<<RNG * CHK, 256, 0, stream>>>(bucket, rtot, hist);
    sum_hist_dinv_k<<<nb, 256, 0, stream>>>(hist, cnt, dinv, bsum, N);
    scan_off_pad_k<<<nb, 256, 0, stream>>>(cnt, bsum, rowptr, hist, col, N);
    fill2_k<<<RNG * CHK, 256, 0, stream>>>(bucket, rtot, hist, col);

    // GCN layer 1..3 (gemm -> packed fp8 -> gather-agg with permuted bias)
    gemm2_k<128, 128, 0, true><<<GG128, 256, 0, stream>>>(
        x, 128, W1t, dinv, nullptr, nullptr, hpr8, N, NT);
    agg128_k<true><<<(N + 3) / 4, 256, 0, stream>>>(hpr8, rowptr, col, dinv, b1p, h, N, Ecap);
    gemm2_k<128, 128, 0, false><<<GG128, 256, 0, stream>>>(
        h, 128, W2t, dinv, nullptr, nullptr, hpr8, N, NT);
    agg128_k<true><<<(N + 3) / 4, 256, 0, stream>>>(hpr8, rowptr, col, dinv, b2p, h, N, Ecap);
    gemm2_k<128, 64, 0, false><<<GG64, 256, 0, stream>>>(
        h, 128, W3t, dinv, nullptr, nullptr, hpr8, N, NT);
    agg64_k<<<(N + 3) / 4, 256, 0, stream>>>(hpr8, rowptr, col, dinv, b3p, h3, N, Ecap);

    // actor+critic heads, one launch (h3 -> out)
    headsB_k<<<2 * GH, 256, 0, stream>>>(
        h3, Wh1t, ba1, bc1, Wa2t, ba2, Wc2t, bc2, Wa3, ba3, Wc3, bc3, out, N, NT, GH);
}